// Round 9
// baseline (1171.661 us; speedup 1.0000x reference)
//
#include <hip/hip_runtime.h>
#include <hip/hip_bf16.h>
#include <math.h>

#define N_ 40000
#define E_ 640000
#define CB_ 400   // k_coarse partial blocks
#define CR_ 100   // rows per block (CB_*CR_ == N_)

typedef short bf16x8 __attribute__((ext_vector_type(8)));
typedef float floatx4 __attribute__((ext_vector_type(4)));

__device__ __forceinline__ short f2bf(float f) {
    __hip_bfloat16 h = __float2bfloat16(f);
    return *reinterpret_cast<short*>(&h);
}
__device__ __forceinline__ float bf2f(short u) {
    unsigned int x = ((unsigned int)(unsigned short)u) << 16;
    return __int_as_float(x);
}
__device__ __forceinline__ float rdlane(float v, int l) {
    return __int_as_float(__builtin_amdgcn_readlane(__float_as_int(v), l));
}
// unpack 2 bf16 packed in a uint
__device__ __forceinline__ float bflo(unsigned int u) { return __int_as_float(u << 16); }
__device__ __forceinline__ float bfhi(unsigned int u) { return __int_as_float(u & 0xffff0000u); }

// ---------------- CSR build ----------------
__global__ void k_count(const int* __restrict__ dst, int* __restrict__ counts) {
    for (int e = blockIdx.x * blockDim.x + threadIdx.x; e < E_; e += gridDim.x * blockDim.x)
        atomicAdd(&counts[dst[e]], 1);
}

__global__ void k_scan(const int* __restrict__ counts, int* __restrict__ rowptr,
                       int* __restrict__ cursor) {
    __shared__ int buf[1024];
    int t = threadIdx.x;
    int carry = 0;
    for (int base = 0; base < N_; base += 1024) {
        int i = base + t;
        int v = (i < N_) ? counts[i] : 0;
        buf[t] = v;
        __syncthreads();
        for (int off = 1; off < 1024; off <<= 1) {
            int add = (t >= off) ? buf[t - off] : 0;
            __syncthreads();
            buf[t] += add;
            __syncthreads();
        }
        int incl = buf[t];
        int excl = incl - v;
        if (i < N_) { rowptr[i] = carry + excl; cursor[i] = carry + excl; }
        int total = buf[1023];
        __syncthreads();
        carry += total;
    }
    if (t == 0) rowptr[N_] = carry;
}

__global__ void k_fill(const int* __restrict__ src, const int* __restrict__ dst,
                       int* __restrict__ cursor, int* __restrict__ srcv) {
    for (int e = blockIdx.x * blockDim.x + threadIdx.x; e < E_; e += gridDim.x * blockDim.x) {
        int d = dst[e];
        int pos = atomicAdd(&cursor[d], 1);
        srcv[pos] = src[e];
    }
}

// ---------------- GEMM [N,128] x [128,128] (+bias), fp32 out ----------------
__global__ __launch_bounds__(256) void k_gemm128(const float* __restrict__ A,
                                                 const float* __restrict__ W,
                                                 const float* __restrict__ bias,
                                                 float* __restrict__ C) {
    __shared__ float As[8 * 128];
    int t = threadIdx.x;
    int r0 = blockIdx.x * 8;
    *(float4*)(As + t * 4) = *(const float4*)(A + (size_t)r0 * 128 + t * 4);
    __syncthreads();
    int c = t & 127, g = t >> 7;
    float a0 = 0.f, a1 = 0.f, a2 = 0.f, a3 = 0.f;
#pragma unroll 4
    for (int k = 0; k < 128; k++) {
        float wv = W[k * 128 + c];
        a0 += As[(g * 4 + 0) * 128 + k] * wv;
        a1 += As[(g * 4 + 1) * 128 + k] * wv;
        a2 += As[(g * 4 + 2) * 128 + k] * wv;
        a3 += As[(g * 4 + 3) * 128 + k] * wv;
    }
    float bv = bias ? bias[c] : 0.f;
    C[(size_t)(r0 + g * 4 + 0) * 128 + c] = a0 + bv;
    C[(size_t)(r0 + g * 4 + 1) * 128 + c] = a1 + bv;
    C[(size_t)(r0 + g * 4 + 2) * 128 + c] = a2 + bv;
    C[(size_t)(r0 + g * 4 + 3) * 128 + c] = a3 + bv;
}

// ---------------- GEMM variant: bf16 output ----------------
__global__ __launch_bounds__(256) void k_gemm128b(const float* __restrict__ A,
                                                  const float* __restrict__ W,
                                                  const float* __restrict__ bias,
                                                  short* __restrict__ C) {
    __shared__ float As[8 * 128];
    int t = threadIdx.x;
    int r0 = blockIdx.x * 8;
    *(float4*)(As + t * 4) = *(const float4*)(A + (size_t)r0 * 128 + t * 4);
    __syncthreads();
    int c = t & 127, g = t >> 7;
    float a0 = 0.f, a1 = 0.f, a2 = 0.f, a3 = 0.f;
#pragma unroll 4
    for (int k = 0; k < 128; k++) {
        float wv = W[k * 128 + c];
        a0 += As[(g * 4 + 0) * 128 + k] * wv;
        a1 += As[(g * 4 + 1) * 128 + k] * wv;
        a2 += As[(g * 4 + 2) * 128 + k] * wv;
        a3 += As[(g * 4 + 3) * 128 + k] * wv;
    }
    float bv = bias ? bias[c] : 0.f;
    C[(size_t)(r0 + g * 4 + 0) * 128 + c] = f2bf(a0 + bv);
    C[(size_t)(r0 + g * 4 + 1) * 128 + c] = f2bf(a1 + bv);
    C[(size_t)(r0 + g * 4 + 2) * 128 + c] = f2bf(a2 + bv);
    C[(size_t)(r0 + g * 4 + 3) * 128 + c] = f2bf(a3 + bv);
}

// ---------------- logits GEMM [N,128] x [128,100] (+bias) ----------------
__global__ __launch_bounds__(256) void k_gemm100(const float* __restrict__ A,
                                                 const float* __restrict__ W,
                                                 const float* __restrict__ bias,
                                                 float* __restrict__ C) {
    __shared__ float As[8 * 128];
    int t = threadIdx.x;
    int r0 = blockIdx.x * 8;
    *(float4*)(As + t * 4) = *(const float4*)(A + (size_t)r0 * 128 + t * 4);
    __syncthreads();
    int c = t & 127, g = t >> 7;
    if (c >= 100) return;
    float a0 = 0.f, a1 = 0.f, a2 = 0.f, a3 = 0.f;
#pragma unroll 4
    for (int k = 0; k < 128; k++) {
        float wv = W[k * 100 + c];
        a0 += As[(g * 4 + 0) * 128 + k] * wv;
        a1 += As[(g * 4 + 1) * 128 + k] * wv;
        a2 += As[(g * 4 + 2) * 128 + k] * wv;
        a3 += As[(g * 4 + 3) * 128 + k] * wv;
    }
    float bv = bias[c];
    C[(size_t)(r0 + g * 4 + 0) * 100 + c] = a0 + bv;
    C[(size_t)(r0 + g * 4 + 1) * 100 + c] = a1 + bv;
    C[(size_t)(r0 + g * 4 + 2) * 100 + c] = a2 + bv;
    C[(size_t)(r0 + g * 4 + 3) * 100 + c] = a3 + bv;
}

// ---------------- softmax over 100 logits, wave per node, barrier-free ----------------
__global__ __launch_bounds__(256) void k_smax100(const float* __restrict__ logits,
                                                 float* __restrict__ s) {
    int lane = threadIdx.x & 63;
    int n = blockIdx.x * 4 + (threadIdx.x >> 6);
    if (n >= N_) return;
    bool act = lane < 50;
    float2 v = make_float2(-INFINITY, -INFINITY);
    if (act) v = *(const float2*)(logits + (size_t)n * 100 + 2 * lane);
    float mx = fmaxf(v.x, v.y);
#pragma unroll
    for (int off = 1; off < 64; off <<= 1) mx = fmaxf(mx, __shfl_xor(mx, off));
    float e0 = act ? __expf(v.x - mx) : 0.f;
    float e1 = act ? __expf(v.y - mx) : 0.f;
    float sm = e0 + e1;
#pragma unroll
    for (int off = 1; off < 64; off <<= 1) sm += __shfl_xor(sm, off);
    float inv = 1.f / sm;
    if (act) *(float2*)(s + (size_t)n * 100 + 2 * lane) = make_float2(e0 * inv, e1 * inv);
}

// ---------------- per-node attention logits el/er (bf16 feat) ----------------
template <int H>
__global__ __launch_bounds__(256) void k_elr(const short* __restrict__ feat,
                                             const float* __restrict__ al,
                                             const float* __restrict__ ar,
                                             float* __restrict__ el, float* __restrict__ er) {
    int lane = threadIdx.x & 63;
    int n = blockIdx.x * 4 + (threadIdx.x >> 6);
    if (n >= N_) return;
    unsigned int u = *(const unsigned int*)(feat + (size_t)n * 128 + 2 * lane);
    float fx = bflo(u), fy = bfhi(u);
    float2 a = *(const float2*)(al + 2 * lane);
    float2 b = *(const float2*)(ar + 2 * lane);
    float pl = fx * a.x + fy * a.y;
    float pr = fx * b.x + fy * b.y;
    constexpr int G = 64 / H;
#pragma unroll
    for (int off = 1; off < G; off <<= 1) {
        pl += __shfl_xor(pl, off);
        pr += __shfl_xor(pr, off);
    }
    if ((lane & (G - 1)) == 0) {
        int hh = lane / G;
        el[(size_t)n * H + hh] = pl;
        er[(size_t)n * H + hh] = pr;
    }
}

// ---------------- GAT edge-softmax + aggregate (wave per dst node, bf16 feat) ----------------
template <int H>
__global__ __launch_bounds__(256) void k_gat_agg(const short* __restrict__ feat,
                                                 const float* __restrict__ el,
                                                 const float* __restrict__ er,
                                                 const int* __restrict__ rowptr,
                                                 const int* __restrict__ srcv,
                                                 const float* __restrict__ bias,
                                                 float* __restrict__ xout) {
    int lane = threadIdx.x & 63;
    int n = blockIdx.x * 4 + (threadIdx.x >> 6);
    if (n >= N_) return;
    int beg = rowptr[n], end = rowptr[n + 1];
    int f0 = 2 * lane;
    if (beg == end) {
        *(float2*)(xout + (size_t)n * 128 + f0) = *(const float2*)(bias + f0);
        return;
    }
    constexpr int LH = (H == 8) ? 3 : 0;
    int h = lane & (H - 1);
    float ern = er[(size_t)n * H + h];
    float m = -INFINITY, ss = 0.f;
    for (int e = beg + (lane >> LH); e < end; e += (64 >> LH)) {
        int sI = srcv[e];
        float x = el[(size_t)sI * H + h] + ern;
        float lr = x > 0.f ? x : 0.2f * x;
        if (lr > m) { ss = ss * __expf(m - lr) + 1.f; m = lr; }
        else ss += __expf(lr - m);
    }
#pragma unroll
    for (int off = H; off < 64; off <<= 1) {
        float om = __shfl_xor(m, off);
        float os = __shfl_xor(ss, off);
        float nm = fmaxf(m, om);
        float p1 = (m == -INFINITY) ? 0.f : ss * __expf(m - nm);
        float p2 = (om == -INFINITY) ? 0.f : os * __expf(om - nm);
        m = nm; ss = p1 + p2;
    }
    int hf = (lane * H) >> 6;
    float mh = __shfl(m, hf);
    float dh = __shfl(ss, hf);
    float inv_d = 1.f / dh;
    float ernf = er[(size_t)n * H + hf];
    float accx = 0.f, accy = 0.f;
    int e = beg;
    for (; e + 2 <= end; e += 2) {
        int s0 = srcv[e], s1 = srcv[e + 1];
        float x0 = el[(size_t)s0 * H + hf] + ernf;
        float x1 = el[(size_t)s1 * H + hf] + ernf;
        unsigned int u0 = *(const unsigned int*)(feat + (size_t)s0 * 128 + f0);
        unsigned int u1 = *(const unsigned int*)(feat + (size_t)s1 * 128 + f0);
        float lr0 = x0 > 0.f ? x0 : 0.2f * x0;
        float lr1 = x1 > 0.f ? x1 : 0.2f * x1;
        float a0 = __expf(lr0 - mh) * inv_d;
        float a1 = __expf(lr1 - mh) * inv_d;
        accx += a0 * bflo(u0) + a1 * bflo(u1);
        accy += a0 * bfhi(u0) + a1 * bfhi(u1);
    }
    if (e < end) {
        int s0 = srcv[e];
        float x0 = el[(size_t)s0 * H + hf] + ernf;
        unsigned int u0 = *(const unsigned int*)(feat + (size_t)s0 * 128 + f0);
        float lr0 = x0 > 0.f ? x0 : 0.2f * x0;
        float a0 = __expf(lr0 - mh) * inv_d;
        accx += a0 * bflo(u0);
        accy += a0 * bfhi(u0);
    }
    float2 b2 = *(const float2*)(bias + f0);
    *(float2*)(xout + (size_t)n * 128 + f0) = make_float2(accx + b2.x, accy + b2.y);
}

// ---------------- BN stats ----------------
__global__ __launch_bounds__(256) void k_bn_stats(const float* __restrict__ x,
                                                  float* __restrict__ sum,
                                                  float* __restrict__ sumsq) {
    __shared__ float ls[256], lq[256];
    int t = threadIdx.x;
    int col = t & 127, half = t >> 7;
    float s = 0.f, q = 0.f;
    for (int r = blockIdx.x * 2 + half; r < N_; r += gridDim.x * 2) {
        float v = x[(size_t)r * 128 + col];
        s += v; q += v * v;
    }
    ls[t] = s; lq[t] = q;
    __syncthreads();
    if (t < 128) {
        atomicAdd(&sum[col], ls[t] + ls[t + 128]);
        atomicAdd(&sumsq[col], lq[t] + lq[t + 128]);
    }
}

// ---------------- BN apply + ELU + residual (+mask) ----------------
__global__ __launch_bounds__(256) void k_bn_apply(const float* __restrict__ x,
                                                  const float* __restrict__ hprev,
                                                  const float* __restrict__ sum,
                                                  const float* __restrict__ sumsq,
                                                  const float* __restrict__ g,
                                                  const float* __restrict__ b,
                                                  float* __restrict__ out, int do_mask) {
    int i = blockIdx.x * blockDim.x + threadIdx.x;
    if (i >= N_ * 128) return;
    int c = i & 127;
    const float invN = 1.f / (float)N_;
    float mu = sum[c] * invN;
    float var = sumsq[c] * invN - mu * mu;
    float inv = rsqrtf(var + 1e-5f);
    float y = g[c] * (x[i] - mu) * inv + b[c];
    y = y > 0.f ? y : (__expf(y) - 1.f);
    float hv = hprev[i] + y;
    if (do_mask && isinf(hv)) hv = 1e9f;
    out[i] = hv;
}

// ---------------- h_coarse partials: part[b] = s[rows]^T @ hf[rows] ----------------
// __launch_bounds__(128,1): full VGPR budget so acc[100] stays in registers
// (default budget gave VGPR_Count=60 -> scratch spill, 85us)
__global__ __launch_bounds__(128, 1) void k_coarse_part(const float* __restrict__ s,
                                                        const float* __restrict__ hf,
                                                        float* __restrict__ part) {
    int t = threadIdx.x;
    int lane = t & 63;
    float acc[100];
#pragma unroll
    for (int a = 0; a < 100; a++) acc[a] = 0.f;
    int n0 = blockIdx.x * CR_;
    for (int n = n0; n < n0 + CR_; n += 2) {
        float hv0 = hf[(size_t)n * 128 + t];
        float hv1 = hf[(size_t)(n + 1) * 128 + t];
        float2 sv0 = make_float2(0.f, 0.f), sv1 = make_float2(0.f, 0.f);
        if (lane < 50) {
            sv0 = *(const float2*)(s + (size_t)n * 100 + 2 * lane);
            sv1 = *(const float2*)(s + (size_t)(n + 1) * 100 + 2 * lane);
        }
#pragma unroll
        for (int a = 0; a < 50; ++a) {
            float a0 = rdlane(sv0.x, a), b0 = rdlane(sv0.y, a);
            float a1 = rdlane(sv1.x, a), b1 = rdlane(sv1.y, a);
            acc[2 * a]     += a0 * hv0 + a1 * hv1;
            acc[2 * a + 1] += b0 * hv0 + b1 * hv1;
        }
    }
    float* dstp = part + (size_t)blockIdx.x * 12800 + t;
#pragma unroll
    for (int a = 0; a < 100; a++) dstp[a * 128] = acc[a];
}

// ---------------- reduce partials -> hc[100][128] ----------------
__global__ __launch_bounds__(256) void k_coarse_reduce(const float* __restrict__ part,
                                                       float* __restrict__ hc) {
    int i = blockIdx.x * blockDim.x + threadIdx.x;  // 12800 total
    if (i >= 12800) return;
    float s0 = 0.f, s1 = 0.f, s2 = 0.f, s3 = 0.f;
    for (int b = 0; b < CB_; b += 4) {
        s0 += part[(size_t)(b + 0) * 12800 + i];
        s1 += part[(size_t)(b + 1) * 12800 + i];
        s2 += part[(size_t)(b + 2) * 12800 + i];
        s3 += part[(size_t)(b + 3) * 12800 + i];
    }
    hc[i] = (s0 + s1) + (s2 + s3);
}

// ---------------- h = mask(0.5*h_fine + 0.5*(s@h_coarse)) ----------------
__global__ __launch_bounds__(128) void k_combine(const float* __restrict__ s,
                                                 const float* __restrict__ hc,
                                                 const float* __restrict__ hfine,
                                                 float* __restrict__ hout) {
    __shared__ float ssh[100];
    int n = blockIdx.x, t = threadIdx.x;
    if (t < 100) ssh[t] = s[(size_t)n * 100 + t];
    __syncthreads();
    float acc = 0.f;
    for (int a = 0; a < 100; a++) acc += ssh[a] * hc[a * 128 + t];
    float v = 0.5f * hfine[(size_t)n * 128 + t] + 0.5f * acc;
    if (isinf(v)) v = 1e9f;
    hout[(size_t)n * 128 + t] = v;
}

// ---------------- prep: Wm2 [128][64] fp32 -> Wm2T bf16 [64][128] ----------------
__global__ __launch_bounds__(256) void k_prep_w(const float* __restrict__ Wm2,
                                                short* __restrict__ Wm2T) {
    int i = blockIdx.x * blockDim.x + threadIdx.x;  // 8192 total
    if (i >= 64 * 128) return;
    int n = i & 63, k = i >> 6;
    Wm2T[n * 128 + k] = f2bf(Wm2[k * 64 + n]);
}

// ---------------- edge MLP readout: barrier-free persistent MFMA ----------------
__global__ __launch_bounds__(256) void k_edge_mlp2(const short* __restrict__ Pb,
                                                   const short* __restrict__ Qb,
                                                   const int* __restrict__ src,
                                                   const int* __restrict__ dst,
                                                   const short* __restrict__ Wm2T,
                                                   const float* __restrict__ bm2,
                                                   const float* __restrict__ Wm3,
                                                   const float* __restrict__ bm3,
                                                   float* __restrict__ zout) {
    int lane = threadIdx.x & 63;
    int lm = lane & 15, quad = lane >> 4;
    int gw = (blockIdx.x * blockDim.x + threadIdx.x) >> 6;
    int nw = (gridDim.x * blockDim.x) >> 6;

    bf16x8 bF[4][4];
#pragma unroll
    for (int nt = 0; nt < 4; nt++)
#pragma unroll
        for (int kt = 0; kt < 4; kt++)
            bF[nt][kt] = *(const bf16x8*)(Wm2T + (nt * 16 + lm) * 128 + kt * 32 + quad * 8);
    float bv[4], w30[4], w31[4];
#pragma unroll
    for (int nt = 0; nt < 4; nt++) {
        int n = nt * 16 + lm;
        bv[nt] = bm2[n]; w30[nt] = Wm3[2 * n]; w31[nt] = Wm3[2 * n + 1];
    }
    float b30 = bm3[0], b31 = bm3[1];

    for (int tile = gw; tile < E_ / 16; tile += nw) {
        int e0 = tile * 16;
        int s = src[e0 + lm], d = dst[e0 + lm];
        const short* pr = Pb + (size_t)s * 128 + quad * 8;
        const short* qr = Qb + (size_t)d * 128 + quad * 8;
        bf16x8 aF[4];
#pragma unroll
        for (int kt = 0; kt < 4; kt++) {
            bf16x8 pv = *(const bf16x8*)(pr + kt * 32);
            bf16x8 qv = *(const bf16x8*)(qr + kt * 32);
            bf16x8 o;
#pragma unroll
            for (int j = 0; j < 8; j++) {
                float x = bf2f(pv[j]) + bf2f(qv[j]);
                o[j] = f2bf(fmaxf(x, 0.f));
            }
            aF[kt] = o;
        }
        floatx4 acc[4];
#pragma unroll
        for (int nt = 0; nt < 4; nt++) {
            acc[nt] = (floatx4){0.f, 0.f, 0.f, 0.f};
#pragma unroll
            for (int kt = 0; kt < 4; kt++)
                acc[nt] = __builtin_amdgcn_mfma_f32_16x16x32_bf16(aF[kt], bF[nt][kt], acc[nt], 0, 0, 0);
        }
        float pz0[4] = {0.f, 0.f, 0.f, 0.f};
        float pz1[4] = {0.f, 0.f, 0.f, 0.f};
#pragma unroll
        for (int nt = 0; nt < 4; nt++) {
#pragma unroll
            for (int r = 0; r < 4; r++) {
                float u = fmaxf(acc[nt][r] + bv[nt], 0.f);
                pz0[r] += u * w30[nt];
                pz1[r] += u * w31[nt];
            }
        }
#pragma unroll
        for (int off = 1; off < 16; off <<= 1) {
#pragma unroll
            for (int r = 0; r < 4; r++) {
                pz0[r] += __shfl_xor(pz0[r], off);
                pz1[r] += __shfl_xor(pz1[r], off);
            }
        }
        if (lm < 4) {
            int e = e0 + quad * 4 + lm;
            float z0 = pz0[lm] + b30;
            float z1 = pz1[lm] + b31;
            if (isinf(z0)) z0 = 1e9f;
            if (isinf(z1)) z1 = 1e9f;
            *(float2*)(zout + (size_t)e * 2) = make_float2(z0, z1);
        }
    }
}

extern "C" void kernel_launch(void* const* d_in, const int* in_sizes, int n_in,
                              void* d_out, int out_size, void* d_ws, size_t ws_size,
                              hipStream_t stream) {
    const float* h_in  = (const float*)d_in[0];
    const int*   src   = (const int*)d_in[2];
    const int*   dst   = (const int*)d_in[3];
    const float* W_emb = (const float*)d_in[4];
    const float* b_emb = (const float*)d_in[5];
    const float* Wg    = (const float*)d_in[6];
    const float* alg   = (const float*)d_in[7];
    const float* arg_  = (const float*)d_in[8];
    const float* bg    = (const float*)d_in[9];
    const float* gam   = (const float*)d_in[10];
    const float* bet   = (const float*)d_in[11];
    const float* W3    = (const float*)d_in[12];
    const float* al3   = (const float*)d_in[13];
    const float* ar3   = (const float*)d_in[14];
    const float* b3    = (const float*)d_in[15];
    const float* gam3  = (const float*)d_in[16];
    const float* bet3  = (const float*)d_in[17];
    const float* Wa    = (const float*)d_in[18];
    const float* ba    = (const float*)d_in[19];
    const float* Wm1   = (const float*)d_in[20];
    const float* bm1   = (const float*)d_in[21];
    const float* Wm2   = (const float*)d_in[22];
    const float* bm2   = (const float*)d_in[23];
    const float* Wm3   = (const float*)d_in[24];
    const float* bm3   = (const float*)d_in[25];

    float* zout = (float*)d_out;
    float* sout = zout + (size_t)E_ * 2;

    float* ws = (float*)d_ws;
    size_t o = 0;
    float* h_cur = ws + o; o += (size_t)N_ * 128;
    float* xbuf  = ws + o; o += (size_t)N_ * 128;
    float* featb = ws + o; o += (size_t)N_ * 128;   // reused: bf16 feat, coarse partials, bf16 P/Q
    float* el    = ws + o; o += (size_t)N_ * 8;
    float* er    = ws + o; o += (size_t)N_ * 8;
    float* colsum = ws + o; o += 128;
    float* colsq  = ws + o; o += 128;
    float* hc     = ws + o; o += 100 * 128;
    short* Wm2T = (short*)(ws + o); o += (64 * 128) / 2;
    int* counts = (int*)(ws + o); o += N_;
    int* rowptr = (int*)(ws + o); o += N_ + 4;
    int* cursor = (int*)(ws + o); o += N_;
    int* srcv   = (int*)(ws + o); o += E_;

    short* featw = (short*)featb;  // bf16 per-layer projection

    // ---- CSR build ----
    hipMemsetAsync(counts, 0, N_ * sizeof(int), stream);
    k_count<<<1024, 256, 0, stream>>>(dst, counts);
    k_scan<<<1, 1024, 0, stream>>>(counts, rowptr, cursor);
    k_fill<<<1024, 256, 0, stream>>>(src, dst, cursor, srcv);
    k_prep_w<<<32, 256, 0, stream>>>(Wm2, Wm2T);

    // ---- embedding ----
    k_gemm128<<<N_ / 8, 256, 0, stream>>>(h_in, W_emb, b_emb, h_cur);

    // ---- layer 0 (H=8) ----
    k_gemm128b<<<N_ / 8, 256, 0, stream>>>(h_cur, Wg + 0 * 16384, nullptr, featw);
    k_elr<8><<<N_ / 4, 256, 0, stream>>>(featw, alg + 0 * 128, arg_ + 0 * 128, el, er);
    k_gat_agg<8><<<N_ / 4, 256, 0, stream>>>(featw, el, er, rowptr, srcv, bg + 0 * 128, xbuf);
    hipMemsetAsync(colsum, 0, 256 * sizeof(float), stream);
    k_bn_stats<<<512, 256, 0, stream>>>(xbuf, colsum, colsq);
    k_bn_apply<<<(N_ * 128) / 256, 256, 0, stream>>>(xbuf, h_cur, colsum, colsq,
                                                     gam + 0 * 128, bet + 0 * 128, h_cur, 1);

    // ---- layer 1 (biGAT, H=8) ----
    // s = softmax(h@Wa+ba): GEMM to xbuf (dead here), then wave softmax
    k_gemm100<<<N_ / 8, 256, 0, stream>>>(h_cur, Wa, ba, xbuf);
    k_smax100<<<N_ / 4, 256, 0, stream>>>(xbuf, sout);
    k_gemm128b<<<N_ / 8, 256, 0, stream>>>(h_cur, Wg + 1 * 16384, nullptr, featw);
    k_elr<8><<<N_ / 4, 256, 0, stream>>>(featw, alg + 1 * 128, arg_ + 1 * 128, el, er);
    k_gat_agg<8><<<N_ / 4, 256, 0, stream>>>(featw, el, er, rowptr, srcv, bg + 1 * 128, xbuf);
    hipMemsetAsync(colsum, 0, 256 * sizeof(float), stream);
    k_bn_stats<<<512, 256, 0, stream>>>(xbuf, colsum, colsq);
    k_bn_apply<<<(N_ * 128) / 256, 256, 0, stream>>>(xbuf, h_cur, colsum, colsq,
                                                     gam + 1 * 128, bet + 1 * 128, xbuf, 0);
    k_coarse_part<<<CB_, 128, 0, stream>>>(sout, xbuf, featb);
    k_coarse_reduce<<<50, 256, 0, stream>>>(featb, hc);
    k_combine<<<N_, 128, 0, stream>>>(sout, hc, xbuf, h_cur);

    // ---- layer 2 (H=8) ----
    k_gemm128b<<<N_ / 8, 256, 0, stream>>>(h_cur, Wg + 2 * 16384, nullptr, featw);
    k_elr<8><<<N_ / 4, 256, 0, stream>>>(featw, alg + 2 * 128, arg_ + 2 * 128, el, er);
    k_gat_agg<8><<<N_ / 4, 256, 0, stream>>>(featw, el, er, rowptr, srcv, bg + 2 * 128, xbuf);
    hipMemsetAsync(colsum, 0, 256 * sizeof(float), stream);
    k_bn_stats<<<512, 256, 0, stream>>>(xbuf, colsum, colsq);
    k_bn_apply<<<(N_ * 128) / 256, 256, 0, stream>>>(xbuf, h_cur, colsum, colsq,
                                                     gam + 2 * 128, bet + 2 * 128, h_cur, 1);

    // ---- layer 3 (H=1) ----
    k_gemm128b<<<N_ / 8, 256, 0, stream>>>(h_cur, W3, nullptr, featw);
    k_elr<1><<<N_ / 4, 256, 0, stream>>>(featw, al3, ar3, el, er);
    k_gat_agg<1><<<N_ / 4, 256, 0, stream>>>(featw, el, er, rowptr, srcv, b3, xbuf);
    hipMemsetAsync(colsum, 0, 256 * sizeof(float), stream);
    k_bn_stats<<<512, 256, 0, stream>>>(xbuf, colsum, colsq);
    k_bn_apply<<<(N_ * 128) / 256, 256, 0, stream>>>(xbuf, h_cur, colsum, colsq,
                                                     gam3, bet3, h_cur, 1);

    // ---- edge MLP readout: Pb = bf16(h@Wm1[:128]+bm1), Qb = bf16(h@Wm1[128:]) ----
    short* Pb = (short*)featb;
    short* Qb = Pb + (size_t)N_ * 128;
    k_gemm128b<<<N_ / 8, 256, 0, stream>>>(h_cur, Wm1, bm1, Pb);
    k_gemm128b<<<N_ / 8, 256, 0, stream>>>(h_cur, Wm1 + 128 * 128, nullptr, Qb);
    k_edge_mlp2<<<1024, 256, 0, stream>>>(Pb, Qb, src, dst, Wm2T, bm2, Wm3, bm3, zout);
}

// Round 10
// 1150.403 us; speedup vs baseline: 1.0185x; 1.0185x over previous
//
#include <hip/hip_runtime.h>
#include <hip/hip_bf16.h>
#include <math.h>

#define N_ 40000
#define E_ 640000
#define CB_ 400   // k_coarse partial blocks
#define CR_ 100   // rows per block (CB_*CR_ == N_)

typedef short bf16x8 __attribute__((ext_vector_type(8)));
typedef float floatx4 __attribute__((ext_vector_type(4)));

__device__ __forceinline__ short f2bf(float f) {
    __hip_bfloat16 h = __float2bfloat16(f);
    return *reinterpret_cast<short*>(&h);
}
__device__ __forceinline__ float bf2f(short u) {
    unsigned int x = ((unsigned int)(unsigned short)u) << 16;
    return __int_as_float(x);
}
__device__ __forceinline__ float rdlane(float v, int l) {
    return __int_as_float(__builtin_amdgcn_readlane(__float_as_int(v), l));
}
// unpack 2 bf16 packed in a uint
__device__ __forceinline__ float bflo(unsigned int u) { return __int_as_float(u << 16); }
__device__ __forceinline__ float bfhi(unsigned int u) { return __int_as_float(u & 0xffff0000u); }

// ---------------- CSR build ----------------
__global__ void k_count(const int* __restrict__ dst, int* __restrict__ counts) {
    for (int e = blockIdx.x * blockDim.x + threadIdx.x; e < E_; e += gridDim.x * blockDim.x)
        atomicAdd(&counts[dst[e]], 1);
}

__global__ void k_scan(const int* __restrict__ counts, int* __restrict__ rowptr,
                       int* __restrict__ cursor) {
    __shared__ int buf[1024];
    int t = threadIdx.x;
    int carry = 0;
    for (int base = 0; base < N_; base += 1024) {
        int i = base + t;
        int v = (i < N_) ? counts[i] : 0;
        buf[t] = v;
        __syncthreads();
        for (int off = 1; off < 1024; off <<= 1) {
            int add = (t >= off) ? buf[t - off] : 0;
            __syncthreads();
            buf[t] += add;
            __syncthreads();
        }
        int incl = buf[t];
        int excl = incl - v;
        if (i < N_) { rowptr[i] = carry + excl; cursor[i] = carry + excl; }
        int total = buf[1023];
        __syncthreads();
        carry += total;
    }
    if (t == 0) rowptr[N_] = carry;
}

__global__ void k_fill(const int* __restrict__ src, const int* __restrict__ dst,
                       int* __restrict__ cursor, int* __restrict__ srcv) {
    for (int e = blockIdx.x * blockDim.x + threadIdx.x; e < E_; e += gridDim.x * blockDim.x) {
        int d = dst[e];
        int pos = atomicAdd(&cursor[d], 1);
        srcv[pos] = src[e];
    }
}

// ---------------- GEMM [N,128] x [128,128] (+bias), fp32 out ----------------
__global__ __launch_bounds__(256) void k_gemm128(const float* __restrict__ A,
                                                 const float* __restrict__ W,
                                                 const float* __restrict__ bias,
                                                 float* __restrict__ C) {
    __shared__ float As[8 * 128];
    int t = threadIdx.x;
    int r0 = blockIdx.x * 8;
    *(float4*)(As + t * 4) = *(const float4*)(A + (size_t)r0 * 128 + t * 4);
    __syncthreads();
    int c = t & 127, g = t >> 7;
    float a0 = 0.f, a1 = 0.f, a2 = 0.f, a3 = 0.f;
#pragma unroll 4
    for (int k = 0; k < 128; k++) {
        float wv = W[k * 128 + c];
        a0 += As[(g * 4 + 0) * 128 + k] * wv;
        a1 += As[(g * 4 + 1) * 128 + k] * wv;
        a2 += As[(g * 4 + 2) * 128 + k] * wv;
        a3 += As[(g * 4 + 3) * 128 + k] * wv;
    }
    float bv = bias ? bias[c] : 0.f;
    C[(size_t)(r0 + g * 4 + 0) * 128 + c] = a0 + bv;
    C[(size_t)(r0 + g * 4 + 1) * 128 + c] = a1 + bv;
    C[(size_t)(r0 + g * 4 + 2) * 128 + c] = a2 + bv;
    C[(size_t)(r0 + g * 4 + 3) * 128 + c] = a3 + bv;
}

// ---------------- GEMM variant: bf16 output ----------------
__global__ __launch_bounds__(256) void k_gemm128b(const float* __restrict__ A,
                                                  const float* __restrict__ W,
                                                  const float* __restrict__ bias,
                                                  short* __restrict__ C) {
    __shared__ float As[8 * 128];
    int t = threadIdx.x;
    int r0 = blockIdx.x * 8;
    *(float4*)(As + t * 4) = *(const float4*)(A + (size_t)r0 * 128 + t * 4);
    __syncthreads();
    int c = t & 127, g = t >> 7;
    float a0 = 0.f, a1 = 0.f, a2 = 0.f, a3 = 0.f;
#pragma unroll 4
    for (int k = 0; k < 128; k++) {
        float wv = W[k * 128 + c];
        a0 += As[(g * 4 + 0) * 128 + k] * wv;
        a1 += As[(g * 4 + 1) * 128 + k] * wv;
        a2 += As[(g * 4 + 2) * 128 + k] * wv;
        a3 += As[(g * 4 + 3) * 128 + k] * wv;
    }
    float bv = bias ? bias[c] : 0.f;
    C[(size_t)(r0 + g * 4 + 0) * 128 + c] = f2bf(a0 + bv);
    C[(size_t)(r0 + g * 4 + 1) * 128 + c] = f2bf(a1 + bv);
    C[(size_t)(r0 + g * 4 + 2) * 128 + c] = f2bf(a2 + bv);
    C[(size_t)(r0 + g * 4 + 3) * 128 + c] = f2bf(a3 + bv);
}

// ---------------- logits GEMM [N,128] x [128,100] (+bias) ----------------
__global__ __launch_bounds__(256) void k_gemm100(const float* __restrict__ A,
                                                 const float* __restrict__ W,
                                                 const float* __restrict__ bias,
                                                 float* __restrict__ C) {
    __shared__ float As[8 * 128];
    int t = threadIdx.x;
    int r0 = blockIdx.x * 8;
    *(float4*)(As + t * 4) = *(const float4*)(A + (size_t)r0 * 128 + t * 4);
    __syncthreads();
    int c = t & 127, g = t >> 7;
    if (c >= 100) return;
    float a0 = 0.f, a1 = 0.f, a2 = 0.f, a3 = 0.f;
#pragma unroll 4
    for (int k = 0; k < 128; k++) {
        float wv = W[k * 100 + c];
        a0 += As[(g * 4 + 0) * 128 + k] * wv;
        a1 += As[(g * 4 + 1) * 128 + k] * wv;
        a2 += As[(g * 4 + 2) * 128 + k] * wv;
        a3 += As[(g * 4 + 3) * 128 + k] * wv;
    }
    float bv = bias[c];
    C[(size_t)(r0 + g * 4 + 0) * 100 + c] = a0 + bv;
    C[(size_t)(r0 + g * 4 + 1) * 100 + c] = a1 + bv;
    C[(size_t)(r0 + g * 4 + 2) * 100 + c] = a2 + bv;
    C[(size_t)(r0 + g * 4 + 3) * 100 + c] = a3 + bv;
}

// ---------------- softmax over 100 logits, wave per node, barrier-free ----------------
__global__ __launch_bounds__(256) void k_smax100(const float* __restrict__ logits,
                                                 float* __restrict__ s) {
    int lane = threadIdx.x & 63;
    int n = blockIdx.x * 4 + (threadIdx.x >> 6);
    if (n >= N_) return;
    bool act = lane < 50;
    float2 v = make_float2(-INFINITY, -INFINITY);
    if (act) v = *(const float2*)(logits + (size_t)n * 100 + 2 * lane);
    float mx = fmaxf(v.x, v.y);
#pragma unroll
    for (int off = 1; off < 64; off <<= 1) mx = fmaxf(mx, __shfl_xor(mx, off));
    float e0 = act ? __expf(v.x - mx) : 0.f;
    float e1 = act ? __expf(v.y - mx) : 0.f;
    float sm = e0 + e1;
#pragma unroll
    for (int off = 1; off < 64; off <<= 1) sm += __shfl_xor(sm, off);
    float inv = 1.f / sm;
    if (act) *(float2*)(s + (size_t)n * 100 + 2 * lane) = make_float2(e0 * inv, e1 * inv);
}

// ---------------- per-node attention logits el/er (bf16 feat) ----------------
template <int H>
__global__ __launch_bounds__(256) void k_elr(const short* __restrict__ feat,
                                             const float* __restrict__ al,
                                             const float* __restrict__ ar,
                                             float* __restrict__ el, float* __restrict__ er) {
    int lane = threadIdx.x & 63;
    int n = blockIdx.x * 4 + (threadIdx.x >> 6);
    if (n >= N_) return;
    unsigned int u = *(const unsigned int*)(feat + (size_t)n * 128 + 2 * lane);
    float fx = bflo(u), fy = bfhi(u);
    float2 a = *(const float2*)(al + 2 * lane);
    float2 b = *(const float2*)(ar + 2 * lane);
    float pl = fx * a.x + fy * a.y;
    float pr = fx * b.x + fy * b.y;
    constexpr int G = 64 / H;
#pragma unroll
    for (int off = 1; off < G; off <<= 1) {
        pl += __shfl_xor(pl, off);
        pr += __shfl_xor(pr, off);
    }
    if ((lane & (G - 1)) == 0) {
        int hh = lane / G;
        el[(size_t)n * H + hh] = pl;
        er[(size_t)n * H + hh] = pr;
    }
}

// ---------------- GAT edge-softmax + aggregate (wave per dst node, bf16 feat) ----------------
template <int H>
__global__ __launch_bounds__(256) void k_gat_agg(const short* __restrict__ feat,
                                                 const float* __restrict__ el,
                                                 const float* __restrict__ er,
                                                 const int* __restrict__ rowptr,
                                                 const int* __restrict__ srcv,
                                                 const float* __restrict__ bias,
                                                 float* __restrict__ xout) {
    int lane = threadIdx.x & 63;
    int n = blockIdx.x * 4 + (threadIdx.x >> 6);
    if (n >= N_) return;
    int beg = rowptr[n], end = rowptr[n + 1];
    int f0 = 2 * lane;
    if (beg == end) {
        *(float2*)(xout + (size_t)n * 128 + f0) = *(const float2*)(bias + f0);
        return;
    }
    constexpr int LH = (H == 8) ? 3 : 0;
    int h = lane & (H - 1);
    float ern = er[(size_t)n * H + h];
    float m = -INFINITY, ss = 0.f;
    for (int e = beg + (lane >> LH); e < end; e += (64 >> LH)) {
        int sI = srcv[e];
        float x = el[(size_t)sI * H + h] + ern;
        float lr = x > 0.f ? x : 0.2f * x;
        if (lr > m) { ss = ss * __expf(m - lr) + 1.f; m = lr; }
        else ss += __expf(lr - m);
    }
#pragma unroll
    for (int off = H; off < 64; off <<= 1) {
        float om = __shfl_xor(m, off);
        float os = __shfl_xor(ss, off);
        float nm = fmaxf(m, om);
        float p1 = (m == -INFINITY) ? 0.f : ss * __expf(m - nm);
        float p2 = (om == -INFINITY) ? 0.f : os * __expf(om - nm);
        m = nm; ss = p1 + p2;
    }
    int hf = (lane * H) >> 6;
    float mh = __shfl(m, hf);
    float dh = __shfl(ss, hf);
    float inv_d = 1.f / dh;
    float ernf = er[(size_t)n * H + hf];
    float accx = 0.f, accy = 0.f;
    int e = beg;
    for (; e + 2 <= end; e += 2) {
        int s0 = srcv[e], s1 = srcv[e + 1];
        float x0 = el[(size_t)s0 * H + hf] + ernf;
        float x1 = el[(size_t)s1 * H + hf] + ernf;
        unsigned int u0 = *(const unsigned int*)(feat + (size_t)s0 * 128 + f0);
        unsigned int u1 = *(const unsigned int*)(feat + (size_t)s1 * 128 + f0);
        float lr0 = x0 > 0.f ? x0 : 0.2f * x0;
        float lr1 = x1 > 0.f ? x1 : 0.2f * x1;
        float a0 = __expf(lr0 - mh) * inv_d;
        float a1 = __expf(lr1 - mh) * inv_d;
        accx += a0 * bflo(u0) + a1 * bflo(u1);
        accy += a0 * bfhi(u0) + a1 * bfhi(u1);
    }
    if (e < end) {
        int s0 = srcv[e];
        float x0 = el[(size_t)s0 * H + hf] + ernf;
        unsigned int u0 = *(const unsigned int*)(feat + (size_t)s0 * 128 + f0);
        float lr0 = x0 > 0.f ? x0 : 0.2f * x0;
        float a0 = __expf(lr0 - mh) * inv_d;
        accx += a0 * bflo(u0);
        accy += a0 * bfhi(u0);
    }
    float2 b2 = *(const float2*)(bias + f0);
    *(float2*)(xout + (size_t)n * 128 + f0) = make_float2(accx + b2.x, accy + b2.y);
}

// ---------------- BN stats ----------------
__global__ __launch_bounds__(256) void k_bn_stats(const float* __restrict__ x,
                                                  float* __restrict__ sum,
                                                  float* __restrict__ sumsq) {
    __shared__ float ls[256], lq[256];
    int t = threadIdx.x;
    int col = t & 127, half = t >> 7;
    float s = 0.f, q = 0.f;
    for (int r = blockIdx.x * 2 + half; r < N_; r += gridDim.x * 2) {
        float v = x[(size_t)r * 128 + col];
        s += v; q += v * v;
    }
    ls[t] = s; lq[t] = q;
    __syncthreads();
    if (t < 128) {
        atomicAdd(&sum[col], ls[t] + ls[t + 128]);
        atomicAdd(&sumsq[col], lq[t] + lq[t + 128]);
    }
}

// ---------------- BN apply + ELU + residual (+mask) ----------------
__global__ __launch_bounds__(256) void k_bn_apply(const float* __restrict__ x,
                                                  const float* __restrict__ hprev,
                                                  const float* __restrict__ sum,
                                                  const float* __restrict__ sumsq,
                                                  const float* __restrict__ g,
                                                  const float* __restrict__ b,
                                                  float* __restrict__ out, int do_mask) {
    int i = blockIdx.x * blockDim.x + threadIdx.x;
    if (i >= N_ * 128) return;
    int c = i & 127;
    const float invN = 1.f / (float)N_;
    float mu = sum[c] * invN;
    float var = sumsq[c] * invN - mu * mu;
    float inv = rsqrtf(var + 1e-5f);
    float y = g[c] * (x[i] - mu) * inv + b[c];
    y = y > 0.f ? y : (__expf(y) - 1.f);
    float hv = hprev[i] + y;
    if (do_mask && isinf(hv)) hv = 1e9f;
    out[i] = hv;
}

// ---------------- h_coarse partials: part[b] = s[rows]^T @ hf[rows] ----------------
// 512 threads = 4 groups x 128 cols; group g owns a in [25g, 25g+25) -> acc[25]/thread
// (acc[100]/thread spilled to scratch at VGPR=60 no matter the launch bounds)
__global__ __launch_bounds__(512) void k_coarse_part(const float* __restrict__ s,
                                                     const float* __restrict__ hf,
                                                     float* __restrict__ part) {
    int t = threadIdx.x;
    int c = t & 127;
    int g = t >> 7;        // 0..3
    int lane = t & 63;
    float acc[25];
#pragma unroll
    for (int a = 0; a < 25; a++) acc[a] = 0.f;
    int n0 = blockIdx.x * CR_;
    for (int n = n0; n < n0 + CR_; n += 2) {
        float hv0 = hf[(size_t)n * 128 + c];
        float hv1 = hf[(size_t)(n + 1) * 128 + c];
        float sv0 = 0.f, sv1 = 0.f;
        if (lane < 25) {
            sv0 = s[(size_t)n * 100 + 25 * g + lane];
            sv1 = s[(size_t)(n + 1) * 100 + 25 * g + lane];
        }
#pragma unroll
        for (int a = 0; a < 25; ++a) {
            float a0 = rdlane(sv0, a);
            float a1 = rdlane(sv1, a);
            acc[a] += a0 * hv0 + a1 * hv1;
        }
    }
    float* dstp = part + (size_t)blockIdx.x * 12800 + (size_t)(25 * g) * 128 + c;
#pragma unroll
    for (int a = 0; a < 25; a++) dstp[a * 128] = acc[a];
}

// ---------------- reduce partials -> hc[100][128] ----------------
__global__ __launch_bounds__(256) void k_coarse_reduce(const float* __restrict__ part,
                                                       float* __restrict__ hc) {
    int i = blockIdx.x * blockDim.x + threadIdx.x;  // 12800 total
    if (i >= 12800) return;
    float s0 = 0.f, s1 = 0.f, s2 = 0.f, s3 = 0.f;
    for (int b = 0; b < CB_; b += 4) {
        s0 += part[(size_t)(b + 0) * 12800 + i];
        s1 += part[(size_t)(b + 1) * 12800 + i];
        s2 += part[(size_t)(b + 2) * 12800 + i];
        s3 += part[(size_t)(b + 3) * 12800 + i];
    }
    hc[i] = (s0 + s1) + (s2 + s3);
}

// ---------------- h = mask(0.5*h_fine + 0.5*(s@h_coarse)) ----------------
__global__ __launch_bounds__(128) void k_combine(const float* __restrict__ s,
                                                 const float* __restrict__ hc,
                                                 const float* __restrict__ hfine,
                                                 float* __restrict__ hout) {
    __shared__ float ssh[100];
    int n = blockIdx.x, t = threadIdx.x;
    if (t < 100) ssh[t] = s[(size_t)n * 100 + t];
    __syncthreads();
    float acc = 0.f;
    for (int a = 0; a < 100; a++) acc += ssh[a] * hc[a * 128 + t];
    float v = 0.5f * hfine[(size_t)n * 128 + t] + 0.5f * acc;
    if (isinf(v)) v = 1e9f;
    hout[(size_t)n * 128 + t] = v;
}

// ---------------- prep: Wm2 [128][64] fp32 -> Wm2T bf16 [64][128] ----------------
__global__ __launch_bounds__(256) void k_prep_w(const float* __restrict__ Wm2,
                                                short* __restrict__ Wm2T) {
    int i = blockIdx.x * blockDim.x + threadIdx.x;  // 8192 total
    if (i >= 64 * 128) return;
    int n = i & 63, k = i >> 6;
    Wm2T[n * 128 + k] = f2bf(Wm2[k * 64 + n]);
}

// ---------------- edge MLP readout: barrier-free persistent MFMA ----------------
__global__ __launch_bounds__(256) void k_edge_mlp2(const short* __restrict__ Pb,
                                                   const short* __restrict__ Qb,
                                                   const int* __restrict__ src,
                                                   const int* __restrict__ dst,
                                                   const short* __restrict__ Wm2T,
                                                   const float* __restrict__ bm2,
                                                   const float* __restrict__ Wm3,
                                                   const float* __restrict__ bm3,
                                                   float* __restrict__ zout) {
    int lane = threadIdx.x & 63;
    int lm = lane & 15, quad = lane >> 4;
    int gw = (blockIdx.x * blockDim.x + threadIdx.x) >> 6;
    int nw = (gridDim.x * blockDim.x) >> 6;

    bf16x8 bF[4][4];
#pragma unroll
    for (int nt = 0; nt < 4; nt++)
#pragma unroll
        for (int kt = 0; kt < 4; kt++)
            bF[nt][kt] = *(const bf16x8*)(Wm2T + (nt * 16 + lm) * 128 + kt * 32 + quad * 8);
    float bv[4], w30[4], w31[4];
#pragma unroll
    for (int nt = 0; nt < 4; nt++) {
        int n = nt * 16 + lm;
        bv[nt] = bm2[n]; w30[nt] = Wm3[2 * n]; w31[nt] = Wm3[2 * n + 1];
    }
    float b30 = bm3[0], b31 = bm3[1];

    for (int tile = gw; tile < E_ / 16; tile += nw) {
        int e0 = tile * 16;
        int s = src[e0 + lm], d = dst[e0 + lm];
        const short* pr = Pb + (size_t)s * 128 + quad * 8;
        const short* qr = Qb + (size_t)d * 128 + quad * 8;
        bf16x8 aF[4];
#pragma unroll
        for (int kt = 0; kt < 4; kt++) {
            bf16x8 pv = *(const bf16x8*)(pr + kt * 32);
            bf16x8 qv = *(const bf16x8*)(qr + kt * 32);
            bf16x8 o;
#pragma unroll
            for (int j = 0; j < 8; j++) {
                float x = bf2f(pv[j]) + bf2f(qv[j]);
                o[j] = f2bf(fmaxf(x, 0.f));
            }
            aF[kt] = o;
        }
        floatx4 acc[4];
#pragma unroll
        for (int nt = 0; nt < 4; nt++) {
            acc[nt] = (floatx4){0.f, 0.f, 0.f, 0.f};
#pragma unroll
            for (int kt = 0; kt < 4; kt++)
                acc[nt] = __builtin_amdgcn_mfma_f32_16x16x32_bf16(aF[kt], bF[nt][kt], acc[nt], 0, 0, 0);
        }
        float pz0[4] = {0.f, 0.f, 0.f, 0.f};
        float pz1[4] = {0.f, 0.f, 0.f, 0.f};
#pragma unroll
        for (int nt = 0; nt < 4; nt++) {
#pragma unroll
            for (int r = 0; r < 4; r++) {
                float u = fmaxf(acc[nt][r] + bv[nt], 0.f);
                pz0[r] += u * w30[nt];
                pz1[r] += u * w31[nt];
            }
        }
#pragma unroll
        for (int off = 1; off < 16; off <<= 1) {
#pragma unroll
            for (int r = 0; r < 4; r++) {
                pz0[r] += __shfl_xor(pz0[r], off);
                pz1[r] += __shfl_xor(pz1[r], off);
            }
        }
        if (lm < 4) {
            int e = e0 + quad * 4 + lm;
            float z0 = pz0[lm] + b30;
            float z1 = pz1[lm] + b31;
            if (isinf(z0)) z0 = 1e9f;
            if (isinf(z1)) z1 = 1e9f;
            *(float2*)(zout + (size_t)e * 2) = make_float2(z0, z1);
        }
    }
}

extern "C" void kernel_launch(void* const* d_in, const int* in_sizes, int n_in,
                              void* d_out, int out_size, void* d_ws, size_t ws_size,
                              hipStream_t stream) {
    const float* h_in  = (const float*)d_in[0];
    const int*   src   = (const int*)d_in[2];
    const int*   dst   = (const int*)d_in[3];
    const float* W_emb = (const float*)d_in[4];
    const float* b_emb = (const float*)d_in[5];
    const float* Wg    = (const float*)d_in[6];
    const float* alg   = (const float*)d_in[7];
    const float* arg_  = (const float*)d_in[8];
    const float* bg    = (const float*)d_in[9];
    const float* gam   = (const float*)d_in[10];
    const float* bet   = (const float*)d_in[11];
    const float* W3    = (const float*)d_in[12];
    const float* al3   = (const float*)d_in[13];
    const float* ar3   = (const float*)d_in[14];
    const float* b3    = (const float*)d_in[15];
    const float* gam3  = (const float*)d_in[16];
    const float* bet3  = (const float*)d_in[17];
    const float* Wa    = (const float*)d_in[18];
    const float* ba    = (const float*)d_in[19];
    const float* Wm1   = (const float*)d_in[20];
    const float* bm1   = (const float*)d_in[21];
    const float* Wm2   = (const float*)d_in[22];
    const float* bm2   = (const float*)d_in[23];
    const float* Wm3   = (const float*)d_in[24];
    const float* bm3   = (const float*)d_in[25];

    float* zout = (float*)d_out;
    float* sout = zout + (size_t)E_ * 2;

    float* ws = (float*)d_ws;
    size_t o = 0;
    float* h_cur = ws + o; o += (size_t)N_ * 128;
    float* xbuf  = ws + o; o += (size_t)N_ * 128;
    float* featb = ws + o; o += (size_t)N_ * 128;   // reused: bf16 feat, coarse partials, bf16 P/Q
    float* el    = ws + o; o += (size_t)N_ * 8;
    float* er    = ws + o; o += (size_t)N_ * 8;
    float* colsum = ws + o; o += 128;
    float* colsq  = ws + o; o += 128;
    float* hc     = ws + o; o += 100 * 128;
    short* Wm2T = (short*)(ws + o); o += (64 * 128) / 2;
    int* counts = (int*)(ws + o); o += N_;
    int* rowptr = (int*)(ws + o); o += N_ + 4;
    int* cursor = (int*)(ws + o); o += N_;
    int* srcv   = (int*)(ws + o); o += E_;

    short* featw = (short*)featb;  // bf16 per-layer projection

    // ---- CSR build ----
    hipMemsetAsync(counts, 0, N_ * sizeof(int), stream);
    k_count<<<1024, 256, 0, stream>>>(dst, counts);
    k_scan<<<1, 1024, 0, stream>>>(counts, rowptr, cursor);
    k_fill<<<1024, 256, 0, stream>>>(src, dst, cursor, srcv);
    k_prep_w<<<32, 256, 0, stream>>>(Wm2, Wm2T);

    // ---- embedding ----
    k_gemm128<<<N_ / 8, 256, 0, stream>>>(h_in, W_emb, b_emb, h_cur);

    // ---- layer 0 (H=8) ----
    k_gemm128b<<<N_ / 8, 256, 0, stream>>>(h_cur, Wg + 0 * 16384, nullptr, featw);
    k_elr<8><<<N_ / 4, 256, 0, stream>>>(featw, alg + 0 * 128, arg_ + 0 * 128, el, er);
    k_gat_agg<8><<<N_ / 4, 256, 0, stream>>>(featw, el, er, rowptr, srcv, bg + 0 * 128, xbuf);
    hipMemsetAsync(colsum, 0, 256 * sizeof(float), stream);
    k_bn_stats<<<512, 256, 0, stream>>>(xbuf, colsum, colsq);
    k_bn_apply<<<(N_ * 128) / 256, 256, 0, stream>>>(xbuf, h_cur, colsum, colsq,
                                                     gam + 0 * 128, bet + 0 * 128, h_cur, 1);

    // ---- layer 1 (biGAT, H=8) ----
    // s = softmax(h@Wa+ba): GEMM to xbuf (dead here), then wave softmax
    k_gemm100<<<N_ / 8, 256, 0, stream>>>(h_cur, Wa, ba, xbuf);
    k_smax100<<<N_ / 4, 256, 0, stream>>>(xbuf, sout);
    k_gemm128b<<<N_ / 8, 256, 0, stream>>>(h_cur, Wg + 1 * 16384, nullptr, featw);
    k_elr<8><<<N_ / 4, 256, 0, stream>>>(featw, alg + 1 * 128, arg_ + 1 * 128, el, er);
    k_gat_agg<8><<<N_ / 4, 256, 0, stream>>>(featw, el, er, rowptr, srcv, bg + 1 * 128, xbuf);
    hipMemsetAsync(colsum, 0, 256 * sizeof(float), stream);
    k_bn_stats<<<512, 256, 0, stream>>>(xbuf, colsum, colsq);
    k_bn_apply<<<(N_ * 128) / 256, 256, 0, stream>>>(xbuf, h_cur, colsum, colsq,
                                                     gam + 1 * 128, bet + 1 * 128, xbuf, 0);
    k_coarse_part<<<CB_, 512, 0, stream>>>(sout, xbuf, featb);
    k_coarse_reduce<<<50, 256, 0, stream>>>(featb, hc);
    k_combine<<<N_, 128, 0, stream>>>(sout, hc, xbuf, h_cur);

    // ---- layer 2 (H=8) ----
    k_gemm128b<<<N_ / 8, 256, 0, stream>>>(h_cur, Wg + 2 * 16384, nullptr, featw);
    k_elr<8><<<N_ / 4, 256, 0, stream>>>(featw, alg + 2 * 128, arg_ + 2 * 128, el, er);
    k_gat_agg<8><<<N_ / 4, 256, 0, stream>>>(featw, el, er, rowptr, srcv, bg + 2 * 128, xbuf);
    hipMemsetAsync(colsum, 0, 256 * sizeof(float), stream);
    k_bn_stats<<<512, 256, 0, stream>>>(xbuf, colsum, colsq);
    k_bn_apply<<<(N_ * 128) / 256, 256, 0, stream>>>(xbuf, h_cur, colsum, colsq,
                                                     gam + 2 * 128, bet + 2 * 128, h_cur, 1);

    // ---- layer 3 (H=1) ----
    k_gemm128b<<<N_ / 8, 256, 0, stream>>>(h_cur, W3, nullptr, featw);
    k_elr<1><<<N_ / 4, 256, 0, stream>>>(featw, al3, ar3, el, er);
    k_gat_agg<1><<<N_ / 4, 256, 0, stream>>>(featw, el, er, rowptr, srcv, b3, xbuf);
    hipMemsetAsync(colsum, 0, 256 * sizeof(float), stream);
    k_bn_stats<<<512, 256, 0, stream>>>(xbuf, colsum, colsq);
    k_bn_apply<<<(N_ * 128) / 256, 256, 0, stream>>>(xbuf, h_cur, colsum, colsq,
                                                     gam3, bet3, h_cur, 1);

    // ---- edge MLP readout: Pb = bf16(h@Wm1[:128]+bm1), Qb = bf16(h@Wm1[128:]) ----
    short* Pb = (short*)featb;
    short* Qb = Pb + (size_t)N_ * 128;
    k_gemm128b<<<N_ / 8, 256, 0, stream>>>(h_cur, Wm1, bm1, Pb);
    k_gemm128b<<<N_ / 8, 256, 0, stream>>>(h_cur, Wm1 + 128 * 128, nullptr, Qb);
    k_edge_mlp2<<<1024, 256, 0, stream>>>(Pb, Qb, src, dst, Wm2T, bm2, Wm3, bm3, zout);
}

// Round 11
// 1126.158 us; speedup vs baseline: 1.0404x; 1.0215x over previous
//
#include <hip/hip_runtime.h>
#include <hip/hip_bf16.h>
#include <math.h>

#define N_ 40000
#define E_ 640000
#define CB_ 400   // k_coarse partial blocks
#define CR_ 100   // rows per block (CB_*CR_ == N_)

typedef short bf16x8 __attribute__((ext_vector_type(8)));
typedef float floatx4 __attribute__((ext_vector_type(4)));

__device__ __forceinline__ short f2bf(float f) {
    __hip_bfloat16 h = __float2bfloat16(f);
    return *reinterpret_cast<short*>(&h);
}
__device__ __forceinline__ float bf2f(short u) {
    unsigned int x = ((unsigned int)(unsigned short)u) << 16;
    return __int_as_float(x);
}
__device__ __forceinline__ float rdlane(float v, int l) {
    return __int_as_float(__builtin_amdgcn_readlane(__float_as_int(v), l));
}
// unpack 2 bf16 packed in a uint
__device__ __forceinline__ float bflo(unsigned int u) { return __int_as_float(u << 16); }
__device__ __forceinline__ float bfhi(unsigned int u) { return __int_as_float(u & 0xffff0000u); }

// ---------------- CSR build ----------------
__global__ void k_count(const int* __restrict__ dst, int* __restrict__ counts) {
    for (int e = blockIdx.x * blockDim.x + threadIdx.x; e < E_; e += gridDim.x * blockDim.x)
        atomicAdd(&counts[dst[e]], 1);
}

__global__ void k_scan(const int* __restrict__ counts, int* __restrict__ rowptr,
                       int* __restrict__ cursor) {
    __shared__ int buf[1024];
    int t = threadIdx.x;
    int carry = 0;
    for (int base = 0; base < N_; base += 1024) {
        int i = base + t;
        int v = (i < N_) ? counts[i] : 0;
        buf[t] = v;
        __syncthreads();
        for (int off = 1; off < 1024; off <<= 1) {
            int add = (t >= off) ? buf[t - off] : 0;
            __syncthreads();
            buf[t] += add;
            __syncthreads();
        }
        int incl = buf[t];
        int excl = incl - v;
        if (i < N_) { rowptr[i] = carry + excl; cursor[i] = carry + excl; }
        int total = buf[1023];
        __syncthreads();
        carry += total;
    }
    if (t == 0) rowptr[N_] = carry;
}

__global__ void k_fill(const int* __restrict__ src, const int* __restrict__ dst,
                       int* __restrict__ cursor, int* __restrict__ srcv,
                       unsigned short* __restrict__ dstv, int* __restrict__ eidv) {
    for (int e = blockIdx.x * blockDim.x + threadIdx.x; e < E_; e += gridDim.x * blockDim.x) {
        int d = dst[e];
        int pos = atomicAdd(&cursor[d], 1);
        srcv[pos] = src[e];
        dstv[pos] = (unsigned short)d;
        eidv[pos] = e;
    }
}

// ---------------- GEMM [N,128] x [128,128] (+bias), fp32 out ----------------
__global__ __launch_bounds__(256) void k_gemm128(const float* __restrict__ A,
                                                 const float* __restrict__ W,
                                                 const float* __restrict__ bias,
                                                 float* __restrict__ C) {
    __shared__ float As[8 * 128];
    int t = threadIdx.x;
    int r0 = blockIdx.x * 8;
    *(float4*)(As + t * 4) = *(const float4*)(A + (size_t)r0 * 128 + t * 4);
    __syncthreads();
    int c = t & 127, g = t >> 7;
    float a0 = 0.f, a1 = 0.f, a2 = 0.f, a3 = 0.f;
#pragma unroll 4
    for (int k = 0; k < 128; k++) {
        float wv = W[k * 128 + c];
        a0 += As[(g * 4 + 0) * 128 + k] * wv;
        a1 += As[(g * 4 + 1) * 128 + k] * wv;
        a2 += As[(g * 4 + 2) * 128 + k] * wv;
        a3 += As[(g * 4 + 3) * 128 + k] * wv;
    }
    float bv = bias ? bias[c] : 0.f;
    C[(size_t)(r0 + g * 4 + 0) * 128 + c] = a0 + bv;
    C[(size_t)(r0 + g * 4 + 1) * 128 + c] = a1 + bv;
    C[(size_t)(r0 + g * 4 + 2) * 128 + c] = a2 + bv;
    C[(size_t)(r0 + g * 4 + 3) * 128 + c] = a3 + bv;
}

// ---------------- GEMM variant: bf16 output ----------------
__global__ __launch_bounds__(256) void k_gemm128b(const float* __restrict__ A,
                                                  const float* __restrict__ W,
                                                  const float* __restrict__ bias,
                                                  short* __restrict__ C) {
    __shared__ float As[8 * 128];
    int t = threadIdx.x;
    int r0 = blockIdx.x * 8;
    *(float4*)(As + t * 4) = *(const float4*)(A + (size_t)r0 * 128 + t * 4);
    __syncthreads();
    int c = t & 127, g = t >> 7;
    float a0 = 0.f, a1 = 0.f, a2 = 0.f, a3 = 0.f;
#pragma unroll 4
    for (int k = 0; k < 128; k++) {
        float wv = W[k * 128 + c];
        a0 += As[(g * 4 + 0) * 128 + k] * wv;
        a1 += As[(g * 4 + 1) * 128 + k] * wv;
        a2 += As[(g * 4 + 2) * 128 + k] * wv;
        a3 += As[(g * 4 + 3) * 128 + k] * wv;
    }
    float bv = bias ? bias[c] : 0.f;
    C[(size_t)(r0 + g * 4 + 0) * 128 + c] = f2bf(a0 + bv);
    C[(size_t)(r0 + g * 4 + 1) * 128 + c] = f2bf(a1 + bv);
    C[(size_t)(r0 + g * 4 + 2) * 128 + c] = f2bf(a2 + bv);
    C[(size_t)(r0 + g * 4 + 3) * 128 + c] = f2bf(a3 + bv);
}

// ---------------- logits GEMM [N,128] x [128,100] (+bias) ----------------
__global__ __launch_bounds__(256) void k_gemm100(const float* __restrict__ A,
                                                 const float* __restrict__ W,
                                                 const float* __restrict__ bias,
                                                 float* __restrict__ C) {
    __shared__ float As[8 * 128];
    int t = threadIdx.x;
    int r0 = blockIdx.x * 8;
    *(float4*)(As + t * 4) = *(const float4*)(A + (size_t)r0 * 128 + t * 4);
    __syncthreads();
    int c = t & 127, g = t >> 7;
    if (c >= 100) return;
    float a0 = 0.f, a1 = 0.f, a2 = 0.f, a3 = 0.f;
#pragma unroll 4
    for (int k = 0; k < 128; k++) {
        float wv = W[k * 100 + c];
        a0 += As[(g * 4 + 0) * 128 + k] * wv;
        a1 += As[(g * 4 + 1) * 128 + k] * wv;
        a2 += As[(g * 4 + 2) * 128 + k] * wv;
        a3 += As[(g * 4 + 3) * 128 + k] * wv;
    }
    float bv = bias[c];
    C[(size_t)(r0 + g * 4 + 0) * 100 + c] = a0 + bv;
    C[(size_t)(r0 + g * 4 + 1) * 100 + c] = a1 + bv;
    C[(size_t)(r0 + g * 4 + 2) * 100 + c] = a2 + bv;
    C[(size_t)(r0 + g * 4 + 3) * 100 + c] = a3 + bv;
}

// ---------------- softmax over 100 logits, wave per node, barrier-free ----------------
__global__ __launch_bounds__(256) void k_smax100(const float* __restrict__ logits,
                                                 float* __restrict__ s) {
    int lane = threadIdx.x & 63;
    int n = blockIdx.x * 4 + (threadIdx.x >> 6);
    if (n >= N_) return;
    bool act = lane < 50;
    float2 v = make_float2(-INFINITY, -INFINITY);
    if (act) v = *(const float2*)(logits + (size_t)n * 100 + 2 * lane);
    float mx = fmaxf(v.x, v.y);
#pragma unroll
    for (int off = 1; off < 64; off <<= 1) mx = fmaxf(mx, __shfl_xor(mx, off));
    float e0 = act ? __expf(v.x - mx) : 0.f;
    float e1 = act ? __expf(v.y - mx) : 0.f;
    float sm = e0 + e1;
#pragma unroll
    for (int off = 1; off < 64; off <<= 1) sm += __shfl_xor(sm, off);
    float inv = 1.f / sm;
    if (act) *(float2*)(s + (size_t)n * 100 + 2 * lane) = make_float2(e0 * inv, e1 * inv);
}

// ---------------- per-node attention logits el/er (bf16 feat) ----------------
template <int H>
__global__ __launch_bounds__(256) void k_elr(const short* __restrict__ feat,
                                             const float* __restrict__ al,
                                             const float* __restrict__ ar,
                                             float* __restrict__ el, float* __restrict__ er) {
    int lane = threadIdx.x & 63;
    int n = blockIdx.x * 4 + (threadIdx.x >> 6);
    if (n >= N_) return;
    unsigned int u = *(const unsigned int*)(feat + (size_t)n * 128 + 2 * lane);
    float fx = bflo(u), fy = bfhi(u);
    float2 a = *(const float2*)(al + 2 * lane);
    float2 b = *(const float2*)(ar + 2 * lane);
    float pl = fx * a.x + fy * a.y;
    float pr = fx * b.x + fy * b.y;
    constexpr int G = 64 / H;
#pragma unroll
    for (int off = 1; off < G; off <<= 1) {
        pl += __shfl_xor(pl, off);
        pr += __shfl_xor(pr, off);
    }
    if ((lane & (G - 1)) == 0) {
        int hh = lane / G;
        el[(size_t)n * H + hh] = pl;
        er[(size_t)n * H + hh] = pr;
    }
}

// ---------------- GAT edge-softmax + aggregate (wave per dst node, bf16 feat) ----------------
template <int H>
__global__ __launch_bounds__(256) void k_gat_agg(const short* __restrict__ feat,
                                                 const float* __restrict__ el,
                                                 const float* __restrict__ er,
                                                 const int* __restrict__ rowptr,
                                                 const int* __restrict__ srcv,
                                                 const float* __restrict__ bias,
                                                 float* __restrict__ xout) {
    int lane = threadIdx.x & 63;
    int n = blockIdx.x * 4 + (threadIdx.x >> 6);
    if (n >= N_) return;
    int beg = rowptr[n], end = rowptr[n + 1];
    int f0 = 2 * lane;
    if (beg == end) {
        *(float2*)(xout + (size_t)n * 128 + f0) = *(const float2*)(bias + f0);
        return;
    }
    constexpr int LH = (H == 8) ? 3 : 0;
    int h = lane & (H - 1);
    float ern = er[(size_t)n * H + h];
    float m = -INFINITY, ss = 0.f;
    for (int e = beg + (lane >> LH); e < end; e += (64 >> LH)) {
        int sI = srcv[e];
        float x = el[(size_t)sI * H + h] + ern;
        float lr = x > 0.f ? x : 0.2f * x;
        if (lr > m) { ss = ss * __expf(m - lr) + 1.f; m = lr; }
        else ss += __expf(lr - m);
    }
#pragma unroll
    for (int off = H; off < 64; off <<= 1) {
        float om = __shfl_xor(m, off);
        float os = __shfl_xor(ss, off);
        float nm = fmaxf(m, om);
        float p1 = (m == -INFINITY) ? 0.f : ss * __expf(m - nm);
        float p2 = (om == -INFINITY) ? 0.f : os * __expf(om - nm);
        m = nm; ss = p1 + p2;
    }
    int hf = (lane * H) >> 6;
    float mh = __shfl(m, hf);
    float dh = __shfl(ss, hf);
    float inv_d = 1.f / dh;
    float ernf = er[(size_t)n * H + hf];
    float accx = 0.f, accy = 0.f;
    int e = beg;
    for (; e + 2 <= end; e += 2) {
        int s0 = srcv[e], s1 = srcv[e + 1];
        float x0 = el[(size_t)s0 * H + hf] + ernf;
        float x1 = el[(size_t)s1 * H + hf] + ernf;
        unsigned int u0 = *(const unsigned int*)(feat + (size_t)s0 * 128 + f0);
        unsigned int u1 = *(const unsigned int*)(feat + (size_t)s1 * 128 + f0);
        float lr0 = x0 > 0.f ? x0 : 0.2f * x0;
        float lr1 = x1 > 0.f ? x1 : 0.2f * x1;
        float a0 = __expf(lr0 - mh) * inv_d;
        float a1 = __expf(lr1 - mh) * inv_d;
        accx += a0 * bflo(u0) + a1 * bflo(u1);
        accy += a0 * bfhi(u0) + a1 * bfhi(u1);
    }
    if (e < end) {
        int s0 = srcv[e];
        float x0 = el[(size_t)s0 * H + hf] + ernf;
        unsigned int u0 = *(const unsigned int*)(feat + (size_t)s0 * 128 + f0);
        float lr0 = x0 > 0.f ? x0 : 0.2f * x0;
        float a0 = __expf(lr0 - mh) * inv_d;
        accx += a0 * bflo(u0);
        accy += a0 * bfhi(u0);
    }
    float2 b2 = *(const float2*)(bias + f0);
    *(float2*)(xout + (size_t)n * 128 + f0) = make_float2(accx + b2.x, accy + b2.y);
}

// ---------------- BN stats ----------------
__global__ __launch_bounds__(256) void k_bn_stats(const float* __restrict__ x,
                                                  float* __restrict__ sum,
                                                  float* __restrict__ sumsq) {
    __shared__ float ls[256], lq[256];
    int t = threadIdx.x;
    int col = t & 127, half = t >> 7;
    float s = 0.f, q = 0.f;
    for (int r = blockIdx.x * 2 + half; r < N_; r += gridDim.x * 2) {
        float v = x[(size_t)r * 128 + col];
        s += v; q += v * v;
    }
    ls[t] = s; lq[t] = q;
    __syncthreads();
    if (t < 128) {
        atomicAdd(&sum[col], ls[t] + ls[t + 128]);
        atomicAdd(&sumsq[col], lq[t] + lq[t + 128]);
    }
}

// ---------------- BN apply + ELU + residual (+mask) ----------------
__global__ __launch_bounds__(256) void k_bn_apply(const float* __restrict__ x,
                                                  const float* __restrict__ hprev,
                                                  const float* __restrict__ sum,
                                                  const float* __restrict__ sumsq,
                                                  const float* __restrict__ g,
                                                  const float* __restrict__ b,
                                                  float* __restrict__ out, int do_mask) {
    int i = blockIdx.x * blockDim.x + threadIdx.x;
    if (i >= N_ * 128) return;
    int c = i & 127;
    const float invN = 1.f / (float)N_;
    float mu = sum[c] * invN;
    float var = sumsq[c] * invN - mu * mu;
    float inv = rsqrtf(var + 1e-5f);
    float y = g[c] * (x[i] - mu) * inv + b[c];
    y = y > 0.f ? y : (__expf(y) - 1.f);
    float hv = hprev[i] + y;
    if (do_mask && isinf(hv)) hv = 1e9f;
    out[i] = hv;
}

// ---------------- h_coarse partials: part[b] = s[rows]^T @ hf[rows] ----------------
// 512 threads = 4 groups x 128 cols; group g owns a in [25g, 25g+25) -> acc[25]/thread
__global__ __launch_bounds__(512) void k_coarse_part(const float* __restrict__ s,
                                                     const float* __restrict__ hf,
                                                     float* __restrict__ part) {
    int t = threadIdx.x;
    int c = t & 127;
    int g = t >> 7;        // 0..3
    int lane = t & 63;
    float acc[25];
#pragma unroll
    for (int a = 0; a < 25; a++) acc[a] = 0.f;
    int n0 = blockIdx.x * CR_;
    for (int n = n0; n < n0 + CR_; n += 2) {
        float hv0 = hf[(size_t)n * 128 + c];
        float hv1 = hf[(size_t)(n + 1) * 128 + c];
        float sv0 = 0.f, sv1 = 0.f;
        if (lane < 25) {
            sv0 = s[(size_t)n * 100 + 25 * g + lane];
            sv1 = s[(size_t)(n + 1) * 100 + 25 * g + lane];
        }
#pragma unroll
        for (int a = 0; a < 25; ++a) {
            float a0 = rdlane(sv0, a);
            float a1 = rdlane(sv1, a);
            acc[a] += a0 * hv0 + a1 * hv1;
        }
    }
    float* dstp = part + (size_t)blockIdx.x * 12800 + (size_t)(25 * g) * 128 + c;
#pragma unroll
    for (int a = 0; a < 25; a++) dstp[a * 128] = acc[a];
}

// ---------------- reduce partials -> hc[100][128] ----------------
__global__ __launch_bounds__(256) void k_coarse_reduce(const float* __restrict__ part,
                                                       float* __restrict__ hc) {
    int i = blockIdx.x * blockDim.x + threadIdx.x;  // 12800 total
    if (i >= 12800) return;
    float s0 = 0.f, s1 = 0.f, s2 = 0.f, s3 = 0.f;
    for (int b = 0; b < CB_; b += 4) {
        s0 += part[(size_t)(b + 0) * 12800 + i];
        s1 += part[(size_t)(b + 1) * 12800 + i];
        s2 += part[(size_t)(b + 2) * 12800 + i];
        s3 += part[(size_t)(b + 3) * 12800 + i];
    }
    hc[i] = (s0 + s1) + (s2 + s3);
}

// ---------------- h = mask(0.5*h_fine + 0.5*(s@h_coarse)) ----------------
__global__ __launch_bounds__(128) void k_combine(const float* __restrict__ s,
                                                 const float* __restrict__ hc,
                                                 const float* __restrict__ hfine,
                                                 float* __restrict__ hout) {
    __shared__ float ssh[100];
    int n = blockIdx.x, t = threadIdx.x;
    if (t < 100) ssh[t] = s[(size_t)n * 100 + t];
    __syncthreads();
    float acc = 0.f;
    for (int a = 0; a < 100; a++) acc += ssh[a] * hc[a * 128 + t];
    float v = 0.5f * hfine[(size_t)n * 128 + t] + 0.5f * acc;
    if (isinf(v)) v = 1e9f;
    hout[(size_t)n * 128 + t] = v;
}

// ---------------- prep: Wm2 [128][64] fp32 -> Wm2T bf16 [64][128] ----------------
__global__ __launch_bounds__(256) void k_prep_w(const float* __restrict__ Wm2,
                                                short* __restrict__ Wm2T) {
    int i = blockIdx.x * blockDim.x + threadIdx.x;  // 8192 total
    if (i >= 64 * 128) return;
    int n = i & 63, k = i >> 6;
    Wm2T[n * 128 + k] = f2bf(Wm2[k * 64 + n]);
}

// ---------------- edge MLP readout: dst-sorted order, barrier-free persistent MFMA ----------------
// Processes edges in dst-sorted CSR position order: Q[dst] gathers collapse to
// L1-broadcast hits (16 consecutive edges share ~1-2 dst rows); only P stays random.
// z scattered to original edge ids via eidv.
__global__ __launch_bounds__(256) void k_edge_mlp3(const short* __restrict__ Pb,
                                                   const short* __restrict__ Qb,
                                                   const int* __restrict__ srcv,
                                                   const unsigned short* __restrict__ dstv,
                                                   const int* __restrict__ eidv,
                                                   const short* __restrict__ Wm2T,
                                                   const float* __restrict__ bm2,
                                                   const float* __restrict__ Wm3,
                                                   const float* __restrict__ bm3,
                                                   float* __restrict__ zout) {
    int lane = threadIdx.x & 63;
    int lm = lane & 15, quad = lane >> 4;
    int gw = (blockIdx.x * blockDim.x + threadIdx.x) >> 6;
    int nw = (gridDim.x * blockDim.x) >> 6;

    bf16x8 bF[4][4];
#pragma unroll
    for (int nt = 0; nt < 4; nt++)
#pragma unroll
        for (int kt = 0; kt < 4; kt++)
            bF[nt][kt] = *(const bf16x8*)(Wm2T + (nt * 16 + lm) * 128 + kt * 32 + quad * 8);
    float bv[4], w30[4], w31[4];
#pragma unroll
    for (int nt = 0; nt < 4; nt++) {
        int n = nt * 16 + lm;
        bv[nt] = bm2[n]; w30[nt] = Wm3[2 * n]; w31[nt] = Wm3[2 * n + 1];
    }
    float b30 = bm3[0], b31 = bm3[1];

    for (int tile = gw; tile < E_ / 16; tile += nw) {
        int p0 = tile * 16;
        int s = srcv[p0 + lm];
        int d = (int)dstv[p0 + lm];
        const short* pr = Pb + (size_t)s * 128 + quad * 8;
        const short* qr = Qb + (size_t)d * 128 + quad * 8;
        bf16x8 aF[4];
#pragma unroll
        for (int kt = 0; kt < 4; kt++) {
            bf16x8 pv = *(const bf16x8*)(pr + kt * 32);
            bf16x8 qv = *(const bf16x8*)(qr + kt * 32);
            bf16x8 o;
#pragma unroll
            for (int j = 0; j < 8; j++) {
                float x = bf2f(pv[j]) + bf2f(qv[j]);
                o[j] = f2bf(fmaxf(x, 0.f));
            }
            aF[kt] = o;
        }
        floatx4 acc[4];
#pragma unroll
        for (int nt = 0; nt < 4; nt++) {
            acc[nt] = (floatx4){0.f, 0.f, 0.f, 0.f};
#pragma unroll
            for (int kt = 0; kt < 4; kt++)
                acc[nt] = __builtin_amdgcn_mfma_f32_16x16x32_bf16(aF[kt], bF[nt][kt], acc[nt], 0, 0, 0);
        }
        float pz0[4] = {0.f, 0.f, 0.f, 0.f};
        float pz1[4] = {0.f, 0.f, 0.f, 0.f};
#pragma unroll
        for (int nt = 0; nt < 4; nt++) {
#pragma unroll
            for (int r = 0; r < 4; r++) {
                float u = fmaxf(acc[nt][r] + bv[nt], 0.f);
                pz0[r] += u * w30[nt];
                pz1[r] += u * w31[nt];
            }
        }
#pragma unroll
        for (int off = 1; off < 16; off <<= 1) {
#pragma unroll
            for (int r = 0; r < 4; r++) {
                pz0[r] += __shfl_xor(pz0[r], off);
                pz1[r] += __shfl_xor(pz1[r], off);
            }
        }
        if (lm < 4) {
            int eid = eidv[p0 + quad * 4 + lm];
            float z0 = pz0[lm] + b30;
            float z1 = pz1[lm] + b31;
            if (isinf(z0)) z0 = 1e9f;
            if (isinf(z1)) z1 = 1e9f;
            *(float2*)(zout + (size_t)eid * 2) = make_float2(z0, z1);
        }
    }
}

extern "C" void kernel_launch(void* const* d_in, const int* in_sizes, int n_in,
                              void* d_out, int out_size, void* d_ws, size_t ws_size,
                              hipStream_t stream) {
    const float* h_in  = (const float*)d_in[0];
    const int*   src   = (const int*)d_in[2];
    const int*   dst   = (const int*)d_in[3];
    const float* W_emb = (const float*)d_in[4];
    const float* b_emb = (const float*)d_in[5];
    const float* Wg    = (const float*)d_in[6];
    const float* alg   = (const float*)d_in[7];
    const float* arg_  = (const float*)d_in[8];
    const float* bg    = (const float*)d_in[9];
    const float* gam   = (const float*)d_in[10];
    const float* bet   = (const float*)d_in[11];
    const float* W3    = (const float*)d_in[12];
    const float* al3   = (const float*)d_in[13];
    const float* ar3   = (const float*)d_in[14];
    const float* b3    = (const float*)d_in[15];
    const float* gam3  = (const float*)d_in[16];
    const float* bet3  = (const float*)d_in[17];
    const float* Wa    = (const float*)d_in[18];
    const float* ba    = (const float*)d_in[19];
    const float* Wm1   = (const float*)d_in[20];
    const float* bm1   = (const float*)d_in[21];
    const float* Wm2   = (const float*)d_in[22];
    const float* bm2   = (const float*)d_in[23];
    const float* Wm3   = (const float*)d_in[24];
    const float* bm3   = (const float*)d_in[25];

    float* zout = (float*)d_out;
    float* sout = zout + (size_t)E_ * 2;

    float* ws = (float*)d_ws;
    size_t o = 0;
    float* h_cur = ws + o; o += (size_t)N_ * 128;
    float* xbuf  = ws + o; o += (size_t)N_ * 128;
    float* featb = ws + o; o += (size_t)N_ * 128;   // reused: bf16 feat, coarse partials, bf16 P/Q
    float* el    = ws + o; o += (size_t)N_ * 8;
    float* er    = ws + o; o += (size_t)N_ * 8;
    float* colsum = ws + o; o += 128;
    float* colsq  = ws + o; o += 128;
    float* hc     = ws + o; o += 100 * 128;
    short* Wm2T = (short*)(ws + o); o += (64 * 128) / 2;
    int* counts = (int*)(ws + o); o += N_;
    int* rowptr = (int*)(ws + o); o += N_ + 4;
    int* cursor = (int*)(ws + o); o += N_;
    int* srcv   = (int*)(ws + o); o += E_;
    unsigned short* dstv = (unsigned short*)(ws + o); o += E_ / 2;
    int* eidv   = (int*)(ws + o); o += E_;

    short* featw = (short*)featb;  // bf16 per-layer projection

    // ---- CSR build ----
    hipMemsetAsync(counts, 0, N_ * sizeof(int), stream);
    k_count<<<1024, 256, 0, stream>>>(dst, counts);
    k_scan<<<1, 1024, 0, stream>>>(counts, rowptr, cursor);
    k_fill<<<1024, 256, 0, stream>>>(src, dst, cursor, srcv, dstv, eidv);
    k_prep_w<<<32, 256, 0, stream>>>(Wm2, Wm2T);

    // ---- embedding ----
    k_gemm128<<<N_ / 8, 256, 0, stream>>>(h_in, W_emb, b_emb, h_cur);

    // ---- layer 0 (H=8) ----
    k_gemm128b<<<N_ / 8, 256, 0, stream>>>(h_cur, Wg + 0 * 16384, nullptr, featw);
    k_elr<8><<<N_ / 4, 256, 0, stream>>>(featw, alg + 0 * 128, arg_ + 0 * 128, el, er);
    k_gat_agg<8><<<N_ / 4, 256, 0, stream>>>(featw, el, er, rowptr, srcv, bg + 0 * 128, xbuf);
    hipMemsetAsync(colsum, 0, 256 * sizeof(float), stream);
    k_bn_stats<<<512, 256, 0, stream>>>(xbuf, colsum, colsq);
    k_bn_apply<<<(N_ * 128) / 256, 256, 0, stream>>>(xbuf, h_cur, colsum, colsq,
                                                     gam + 0 * 128, bet + 0 * 128, h_cur, 1);

    // ---- layer 1 (biGAT, H=8) ----
    k_gemm100<<<N_ / 8, 256, 0, stream>>>(h_cur, Wa, ba, xbuf);
    k_smax100<<<N_ / 4, 256, 0, stream>>>(xbuf, sout);
    k_gemm128b<<<N_ / 8, 256, 0, stream>>>(h_cur, Wg + 1 * 16384, nullptr, featw);
    k_elr<8><<<N_ / 4, 256, 0, stream>>>(featw, alg + 1 * 128, arg_ + 1 * 128, el, er);
    k_gat_agg<8><<<N_ / 4, 256, 0, stream>>>(featw, el, er, rowptr, srcv, bg + 1 * 128, xbuf);
    hipMemsetAsync(colsum, 0, 256 * sizeof(float), stream);
    k_bn_stats<<<512, 256, 0, stream>>>(xbuf, colsum, colsq);
    k_bn_apply<<<(N_ * 128) / 256, 256, 0, stream>>>(xbuf, h_cur, colsum, colsq,
                                                     gam + 1 * 128, bet + 1 * 128, xbuf, 0);
    k_coarse_part<<<CB_, 512, 0, stream>>>(sout, xbuf, featb);
    k_coarse_reduce<<<50, 256, 0, stream>>>(featb, hc);
    k_combine<<<N_, 128, 0, stream>>>(sout, hc, xbuf, h_cur);

    // ---- layer 2 (H=8) ----
    k_gemm128b<<<N_ / 8, 256, 0, stream>>>(h_cur, Wg + 2 * 16384, nullptr, featw);
    k_elr<8><<<N_ / 4, 256, 0, stream>>>(featw, alg + 2 * 128, arg_ + 2 * 128, el, er);
    k_gat_agg<8><<<N_ / 4, 256, 0, stream>>>(featw, el, er, rowptr, srcv, bg + 2 * 128, xbuf);
    hipMemsetAsync(colsum, 0, 256 * sizeof(float), stream);
    k_bn_stats<<<512, 256, 0, stream>>>(xbuf, colsum, colsq);
    k_bn_apply<<<(N_ * 128) / 256, 256, 0, stream>>>(xbuf, h_cur, colsum, colsq,
                                                     gam + 2 * 128, bet + 2 * 128, h_cur, 1);

    // ---- layer 3 (H=1) ----
    k_gemm128b<<<N_ / 8, 256, 0, stream>>>(h_cur, W3, nullptr, featw);
    k_elr<1><<<N_ / 4, 256, 0, stream>>>(featw, al3, ar3, el, er);
    k_gat_agg<1><<<N_ / 4, 256, 0, stream>>>(featw, el, er, rowptr, srcv, b3, xbuf);
    hipMemsetAsync(colsum, 0, 256 * sizeof(float), stream);
    k_bn_stats<<<512, 256, 0, stream>>>(xbuf, colsum, colsq);
    k_bn_apply<<<(N_ * 128) / 256, 256, 0, stream>>>(xbuf, h_cur, colsum, colsq,
                                                     gam3, bet3, h_cur, 1);

    // ---- edge MLP readout: Pb = bf16(h@Wm1[:128]+bm1), Qb = bf16(h@Wm1[128:]) ----
    short* Pb = (short*)featb;
    short* Qb = Pb + (size_t)N_ * 128;
    k_gemm128b<<<N_ / 8, 256, 0, stream>>>(h_cur, Wm1, bm1, Pb);
    k_gemm128b<<<N_ / 8, 256, 0, stream>>>(h_cur, Wm1 + 128 * 128, nullptr, Qb);
    k_edge_mlp3<<<2048, 256, 0, stream>>>(Pb, Qb, srcv, dstv, eidv, Wm2T, bm2, Wm3, bm3, zout);
}

// Round 12
// 1075.387 us; speedup vs baseline: 1.0895x; 1.0472x over previous
//
#include <hip/hip_runtime.h>
#include <hip/hip_bf16.h>
#include <math.h>

#define N_ 40000
#define E_ 640000
#define CB_ 400   // k_coarse partial blocks
#define CR_ 100   // rows per block (CB_*CR_ == N_)
#define SB_ 256
#define SNB_ 157  // ceil(N_/SB_)

typedef short bf16x8 __attribute__((ext_vector_type(8)));
typedef float floatx4 __attribute__((ext_vector_type(4)));

__device__ __forceinline__ short f2bf(float f) {
    __hip_bfloat16 h = __float2bfloat16(f);
    return *reinterpret_cast<short*>(&h);
}
__device__ __forceinline__ float bf2f(short u) {
    unsigned int x = ((unsigned int)(unsigned short)u) << 16;
    return __int_as_float(x);
}
__device__ __forceinline__ float rdlane(float v, int l) {
    return __int_as_float(__builtin_amdgcn_readlane(__float_as_int(v), l));
}
// unpack 2 bf16 packed in a uint
__device__ __forceinline__ float bflo(unsigned int u) { return __int_as_float(u << 16); }
__device__ __forceinline__ float bfhi(unsigned int u) { return __int_as_float(u & 0xffff0000u); }

// ---------------- CSR build ----------------
__global__ void k_count(const int* __restrict__ dst, int* __restrict__ counts) {
    for (int e = blockIdx.x * blockDim.x + threadIdx.x; e < E_; e += gridDim.x * blockDim.x)
        atomicAdd(&counts[dst[e]], 1);
}

// ---- 3-phase parallel scan (replaces 74us single-block serial scan) ----
__global__ __launch_bounds__(256) void k_scanA(const int* __restrict__ counts,
                                               int* __restrict__ excl,
                                               int* __restrict__ bsum) {
    int t = threadIdx.x;
    int i = blockIdx.x * SB_ + t;
    int v = (i < N_) ? counts[i] : 0;
    int lane = t & 63, wv = t >> 6;
    int x = v;
#pragma unroll
    for (int off = 1; off < 64; off <<= 1) {
        int y = __shfl_up(x, off);
        if (lane >= off) x += y;
    }
    __shared__ int wsum[4];
    __shared__ int woff[4];
    if (lane == 63) wsum[wv] = x;
    __syncthreads();
    if (t == 0) {
        int a = 0;
#pragma unroll
        for (int j = 0; j < 4; j++) { int tv = wsum[j]; woff[j] = a; a += tv; }
        bsum[blockIdx.x] = a;
    }
    __syncthreads();
    if (i < N_) excl[i] = x - v + woff[wv];
}

__global__ __launch_bounds__(256) void k_scanB(int* __restrict__ bsum) {
    int t = threadIdx.x;
    int v = (t < SNB_) ? bsum[t] : 0;
    int lane = t & 63, wv = t >> 6;
    int x = v;
#pragma unroll
    for (int off = 1; off < 64; off <<= 1) {
        int y = __shfl_up(x, off);
        if (lane >= off) x += y;
    }
    __shared__ int wsum[4];
    __shared__ int woff[4];
    if (lane == 63) wsum[wv] = x;
    __syncthreads();
    if (t == 0) {
        int a = 0;
#pragma unroll
        for (int j = 0; j < 4; j++) { int tv = wsum[j]; woff[j] = a; a += tv; }
    }
    __syncthreads();
    if (t < SNB_) bsum[t] = x - v + woff[wv];
}

__global__ __launch_bounds__(256) void k_scanC(const int* __restrict__ excl,
                                               const int* __restrict__ bsum,
                                               int* __restrict__ rowptr,
                                               int* __restrict__ cursor) {
    int i = blockIdx.x * 256 + threadIdx.x;
    if (i < N_) {
        int r = excl[i] + bsum[i / SB_];
        rowptr[i] = r;
        cursor[i] = r;
    }
    if (i == N_) rowptr[N_] = E_;
}

__global__ void k_fill(const int* __restrict__ src, const int* __restrict__ dst,
                       int* __restrict__ cursor, int* __restrict__ srcv,
                       unsigned short* __restrict__ dstv, int* __restrict__ eidv) {
    for (int e = blockIdx.x * blockDim.x + threadIdx.x; e < E_; e += gridDim.x * blockDim.x) {
        int d = dst[e];
        int pos = atomicAdd(&cursor[d], 1);
        srcv[pos] = src[e];
        dstv[pos] = (unsigned short)d;
        eidv[pos] = e;
    }
}

// ---------------- GEMM [N,128] x [128,128] (+bias), fp32 out ----------------
__global__ __launch_bounds__(256) void k_gemm128(const float* __restrict__ A,
                                                 const float* __restrict__ W,
                                                 const float* __restrict__ bias,
                                                 float* __restrict__ C) {
    __shared__ float As[8 * 128];
    int t = threadIdx.x;
    int r0 = blockIdx.x * 8;
    *(float4*)(As + t * 4) = *(const float4*)(A + (size_t)r0 * 128 + t * 4);
    __syncthreads();
    int c = t & 127, g = t >> 7;
    float a0 = 0.f, a1 = 0.f, a2 = 0.f, a3 = 0.f;
#pragma unroll 4
    for (int k = 0; k < 128; k++) {
        float wv = W[k * 128 + c];
        a0 += As[(g * 4 + 0) * 128 + k] * wv;
        a1 += As[(g * 4 + 1) * 128 + k] * wv;
        a2 += As[(g * 4 + 2) * 128 + k] * wv;
        a3 += As[(g * 4 + 3) * 128 + k] * wv;
    }
    float bv = bias ? bias[c] : 0.f;
    C[(size_t)(r0 + g * 4 + 0) * 128 + c] = a0 + bv;
    C[(size_t)(r0 + g * 4 + 1) * 128 + c] = a1 + bv;
    C[(size_t)(r0 + g * 4 + 2) * 128 + c] = a2 + bv;
    C[(size_t)(r0 + g * 4 + 3) * 128 + c] = a3 + bv;
}

// ---------------- GEMM variant: bf16 output ----------------
__global__ __launch_bounds__(256) void k_gemm128b(const float* __restrict__ A,
                                                  const float* __restrict__ W,
                                                  const float* __restrict__ bias,
                                                  short* __restrict__ C) {
    __shared__ float As[8 * 128];
    int t = threadIdx.x;
    int r0 = blockIdx.x * 8;
    *(float4*)(As + t * 4) = *(const float4*)(A + (size_t)r0 * 128 + t * 4);
    __syncthreads();
    int c = t & 127, g = t >> 7;
    float a0 = 0.f, a1 = 0.f, a2 = 0.f, a3 = 0.f;
#pragma unroll 4
    for (int k = 0; k < 128; k++) {
        float wv = W[k * 128 + c];
        a0 += As[(g * 4 + 0) * 128 + k] * wv;
        a1 += As[(g * 4 + 1) * 128 + k] * wv;
        a2 += As[(g * 4 + 2) * 128 + k] * wv;
        a3 += As[(g * 4 + 3) * 128 + k] * wv;
    }
    float bv = bias ? bias[c] : 0.f;
    C[(size_t)(r0 + g * 4 + 0) * 128 + c] = f2bf(a0 + bv);
    C[(size_t)(r0 + g * 4 + 1) * 128 + c] = f2bf(a1 + bv);
    C[(size_t)(r0 + g * 4 + 2) * 128 + c] = f2bf(a2 + bv);
    C[(size_t)(r0 + g * 4 + 3) * 128 + c] = f2bf(a3 + bv);
}

// ---------------- logits GEMM [N,128] x [128,100] (+bias) ----------------
__global__ __launch_bounds__(256) void k_gemm100(const float* __restrict__ A,
                                                 const float* __restrict__ W,
                                                 const float* __restrict__ bias,
                                                 float* __restrict__ C) {
    __shared__ float As[8 * 128];
    int t = threadIdx.x;
    int r0 = blockIdx.x * 8;
    *(float4*)(As + t * 4) = *(const float4*)(A + (size_t)r0 * 128 + t * 4);
    __syncthreads();
    int c = t & 127, g = t >> 7;
    if (c >= 100) return;
    float a0 = 0.f, a1 = 0.f, a2 = 0.f, a3 = 0.f;
#pragma unroll 4
    for (int k = 0; k < 128; k++) {
        float wv = W[k * 100 + c];
        a0 += As[(g * 4 + 0) * 128 + k] * wv;
        a1 += As[(g * 4 + 1) * 128 + k] * wv;
        a2 += As[(g * 4 + 2) * 128 + k] * wv;
        a3 += As[(g * 4 + 3) * 128 + k] * wv;
    }
    float bv = bias[c];
    C[(size_t)(r0 + g * 4 + 0) * 100 + c] = a0 + bv;
    C[(size_t)(r0 + g * 4 + 1) * 100 + c] = a1 + bv;
    C[(size_t)(r0 + g * 4 + 2) * 100 + c] = a2 + bv;
    C[(size_t)(r0 + g * 4 + 3) * 100 + c] = a3 + bv;
}

// ---------------- softmax over 100 logits, wave per node, barrier-free ----------------
__global__ __launch_bounds__(256) void k_smax100(const float* __restrict__ logits,
                                                 float* __restrict__ s) {
    int lane = threadIdx.x & 63;
    int n = blockIdx.x * 4 + (threadIdx.x >> 6);
    if (n >= N_) return;
    bool act = lane < 50;
    float2 v = make_float2(-INFINITY, -INFINITY);
    if (act) v = *(const float2*)(logits + (size_t)n * 100 + 2 * lane);
    float mx = fmaxf(v.x, v.y);
#pragma unroll
    for (int off = 1; off < 64; off <<= 1) mx = fmaxf(mx, __shfl_xor(mx, off));
    float e0 = act ? __expf(v.x - mx) : 0.f;
    float e1 = act ? __expf(v.y - mx) : 0.f;
    float sm = e0 + e1;
#pragma unroll
    for (int off = 1; off < 64; off <<= 1) sm += __shfl_xor(sm, off);
    float inv = 1.f / sm;
    if (act) *(float2*)(s + (size_t)n * 100 + 2 * lane) = make_float2(e0 * inv, e1 * inv);
}

// ---------------- per-node attention logits el/er (bf16 feat) ----------------
template <int H>
__global__ __launch_bounds__(256) void k_elr(const short* __restrict__ feat,
                                             const float* __restrict__ al,
                                             const float* __restrict__ ar,
                                             float* __restrict__ el, float* __restrict__ er) {
    int lane = threadIdx.x & 63;
    int n = blockIdx.x * 4 + (threadIdx.x >> 6);
    if (n >= N_) return;
    unsigned int u = *(const unsigned int*)(feat + (size_t)n * 128 + 2 * lane);
    float fx = bflo(u), fy = bfhi(u);
    float2 a = *(const float2*)(al + 2 * lane);
    float2 b = *(const float2*)(ar + 2 * lane);
    float pl = fx * a.x + fy * a.y;
    float pr = fx * b.x + fy * b.y;
    constexpr int G = 64 / H;
#pragma unroll
    for (int off = 1; off < G; off <<= 1) {
        pl += __shfl_xor(pl, off);
        pr += __shfl_xor(pr, off);
    }
    if ((lane & (G - 1)) == 0) {
        int hh = lane / G;
        el[(size_t)n * H + hh] = pl;
        er[(size_t)n * H + hh] = pr;
    }
}

// ---------------- GAT edge-softmax + aggregate (wave per dst node, bf16 feat) ----------------
template <int H>
__global__ __launch_bounds__(256) void k_gat_agg(const short* __restrict__ feat,
                                                 const float* __restrict__ el,
                                                 const float* __restrict__ er,
                                                 const int* __restrict__ rowptr,
                                                 const int* __restrict__ srcv,
                                                 const float* __restrict__ bias,
                                                 float* __restrict__ xout) {
    int lane = threadIdx.x & 63;
    int n = blockIdx.x * 4 + (threadIdx.x >> 6);
    if (n >= N_) return;
    int beg = rowptr[n], end = rowptr[n + 1];
    int f0 = 2 * lane;
    if (beg == end) {
        *(float2*)(xout + (size_t)n * 128 + f0) = *(const float2*)(bias + f0);
        return;
    }
    constexpr int LH = (H == 8) ? 3 : 0;
    int h = lane & (H - 1);
    float ern = er[(size_t)n * H + h];
    float m = -INFINITY, ss = 0.f;
    for (int e = beg + (lane >> LH); e < end; e += (64 >> LH)) {
        int sI = srcv[e];
        float x = el[(size_t)sI * H + h] + ern;
        float lr = x > 0.f ? x : 0.2f * x;
        if (lr > m) { ss = ss * __expf(m - lr) + 1.f; m = lr; }
        else ss += __expf(lr - m);
    }
#pragma unroll
    for (int off = H; off < 64; off <<= 1) {
        float om = __shfl_xor(m, off);
        float os = __shfl_xor(ss, off);
        float nm = fmaxf(m, om);
        float p1 = (m == -INFINITY) ? 0.f : ss * __expf(m - nm);
        float p2 = (om == -INFINITY) ? 0.f : os * __expf(om - nm);
        m = nm; ss = p1 + p2;
    }
    int hf = (lane * H) >> 6;
    float mh = __shfl(m, hf);
    float dh = __shfl(ss, hf);
    float inv_d = 1.f / dh;
    float ernf = er[(size_t)n * H + hf];
    float accx = 0.f, accy = 0.f;
    int e = beg;
    for (; e + 2 <= end; e += 2) {
        int s0 = srcv[e], s1 = srcv[e + 1];
        float x0 = el[(size_t)s0 * H + hf] + ernf;
        float x1 = el[(size_t)s1 * H + hf] + ernf;
        unsigned int u0 = *(const unsigned int*)(feat + (size_t)s0 * 128 + f0);
        unsigned int u1 = *(const unsigned int*)(feat + (size_t)s1 * 128 + f0);
        float lr0 = x0 > 0.f ? x0 : 0.2f * x0;
        float lr1 = x1 > 0.f ? x1 : 0.2f * x1;
        float a0 = __expf(lr0 - mh) * inv_d;
        float a1 = __expf(lr1 - mh) * inv_d;
        accx += a0 * bflo(u0) + a1 * bflo(u1);
        accy += a0 * bfhi(u0) + a1 * bfhi(u1);
    }
    if (e < end) {
        int s0 = srcv[e];
        float x0 = el[(size_t)s0 * H + hf] + ernf;
        unsigned int u0 = *(const unsigned int*)(feat + (size_t)s0 * 128 + f0);
        float lr0 = x0 > 0.f ? x0 : 0.2f * x0;
        float a0 = __expf(lr0 - mh) * inv_d;
        accx += a0 * bflo(u0);
        accy += a0 * bfhi(u0);
    }
    float2 b2 = *(const float2*)(bias + f0);
    *(float2*)(xout + (size_t)n * 128 + f0) = make_float2(accx + b2.x, accy + b2.y);
}

// ---------------- BN stats ----------------
__global__ __launch_bounds__(256) void k_bn_stats(const float* __restrict__ x,
                                                  float* __restrict__ sum,
                                                  float* __restrict__ sumsq) {
    __shared__ float ls[256], lq[256];
    int t = threadIdx.x;
    int col = t & 127, half = t >> 7;
    float s = 0.f, q = 0.f;
    for (int r = blockIdx.x * 2 + half; r < N_; r += gridDim.x * 2) {
        float v = x[(size_t)r * 128 + col];
        s += v; q += v * v;
    }
    ls[t] = s; lq[t] = q;
    __syncthreads();
    if (t < 128) {
        atomicAdd(&sum[col], ls[t] + ls[t + 128]);
        atomicAdd(&sumsq[col], lq[t] + lq[t + 128]);
    }
}

// ---------------- BN apply + ELU + residual (+mask) ----------------
__global__ __launch_bounds__(256) void k_bn_apply(const float* __restrict__ x,
                                                  const float* __restrict__ hprev,
                                                  const float* __restrict__ sum,
                                                  const float* __restrict__ sumsq,
                                                  const float* __restrict__ g,
                                                  const float* __restrict__ b,
                                                  float* __restrict__ out, int do_mask) {
    int i = blockIdx.x * blockDim.x + threadIdx.x;
    if (i >= N_ * 128) return;
    int c = i & 127;
    const float invN = 1.f / (float)N_;
    float mu = sum[c] * invN;
    float var = sumsq[c] * invN - mu * mu;
    float inv = rsqrtf(var + 1e-5f);
    float y = g[c] * (x[i] - mu) * inv + b[c];
    y = y > 0.f ? y : (__expf(y) - 1.f);
    float hv = hprev[i] + y;
    if (do_mask && isinf(hv)) hv = 1e9f;
    out[i] = hv;
}

// ---------------- h_coarse partials: part[b] = s[rows]^T @ hf[rows] ----------------
__global__ __launch_bounds__(512) void k_coarse_part(const float* __restrict__ s,
                                                     const float* __restrict__ hf,
                                                     float* __restrict__ part) {
    int t = threadIdx.x;
    int c = t & 127;
    int g = t >> 7;        // 0..3
    int lane = t & 63;
    float acc[25];
#pragma unroll
    for (int a = 0; a < 25; a++) acc[a] = 0.f;
    int n0 = blockIdx.x * CR_;
    for (int n = n0; n < n0 + CR_; n += 2) {
        float hv0 = hf[(size_t)n * 128 + c];
        float hv1 = hf[(size_t)(n + 1) * 128 + c];
        float sv0 = 0.f, sv1 = 0.f;
        if (lane < 25) {
            sv0 = s[(size_t)n * 100 + 25 * g + lane];
            sv1 = s[(size_t)(n + 1) * 100 + 25 * g + lane];
        }
#pragma unroll
        for (int a = 0; a < 25; ++a) {
            float a0 = rdlane(sv0, a);
            float a1 = rdlane(sv1, a);
            acc[a] += a0 * hv0 + a1 * hv1;
        }
    }
    float* dstp = part + (size_t)blockIdx.x * 12800 + (size_t)(25 * g) * 128 + c;
#pragma unroll
    for (int a = 0; a < 25; a++) dstp[a * 128] = acc[a];
}

// ---------------- reduce partials -> hc[100][128] ----------------
__global__ __launch_bounds__(256) void k_coarse_reduce(const float* __restrict__ part,
                                                       float* __restrict__ hc) {
    int i = blockIdx.x * blockDim.x + threadIdx.x;  // 12800 total
    if (i >= 12800) return;
    float s0 = 0.f, s1 = 0.f, s2 = 0.f, s3 = 0.f;
    for (int b = 0; b < CB_; b += 4) {
        s0 += part[(size_t)(b + 0) * 12800 + i];
        s1 += part[(size_t)(b + 1) * 12800 + i];
        s2 += part[(size_t)(b + 2) * 12800 + i];
        s3 += part[(size_t)(b + 3) * 12800 + i];
    }
    hc[i] = (s0 + s1) + (s2 + s3);
}

// ---------------- h = mask(0.5*h_fine + 0.5*(s@h_coarse)) ----------------
__global__ __launch_bounds__(128) void k_combine(const float* __restrict__ s,
                                                 const float* __restrict__ hc,
                                                 const float* __restrict__ hfine,
                                                 float* __restrict__ hout) {
    __shared__ float ssh[100];
    int n = blockIdx.x, t = threadIdx.x;
    if (t < 100) ssh[t] = s[(size_t)n * 100 + t];
    __syncthreads();
    float acc = 0.f;
    for (int a = 0; a < 100; a++) acc += ssh[a] * hc[a * 128 + t];
    float v = 0.5f * hfine[(size_t)n * 128 + t] + 0.5f * acc;
    if (isinf(v)) v = 1e9f;
    hout[(size_t)n * 128 + t] = v;
}

// ---------------- prep: Wm2 [128][64] fp32 -> Wm2T bf16 [64][128] ----------------
__global__ __launch_bounds__(256) void k_prep_w(const float* __restrict__ Wm2,
                                                short* __restrict__ Wm2T) {
    int i = blockIdx.x * blockDim.x + threadIdx.x;  // 8192 total
    if (i >= 64 * 128) return;
    int n = i & 63, k = i >> 6;
    Wm2T[n * 128 + k] = f2bf(Wm2[k * 64 + n]);
}

// ---------------- edge MLP readout: dst-sorted order, barrier-free persistent MFMA ----------------
__global__ __launch_bounds__(256) void k_edge_mlp3(const short* __restrict__ Pb,
                                                   const short* __restrict__ Qb,
                                                   const int* __restrict__ srcv,
                                                   const unsigned short* __restrict__ dstv,
                                                   const int* __restrict__ eidv,
                                                   const short* __restrict__ Wm2T,
                                                   const float* __restrict__ bm2,
                                                   const float* __restrict__ Wm3,
                                                   const float* __restrict__ bm3,
                                                   float* __restrict__ zout) {
    int lane = threadIdx.x & 63;
    int lm = lane & 15, quad = lane >> 4;
    int gw = (blockIdx.x * blockDim.x + threadIdx.x) >> 6;
    int nw = (gridDim.x * blockDim.x) >> 6;

    bf16x8 bF[4][4];
#pragma unroll
    for (int nt = 0; nt < 4; nt++)
#pragma unroll
        for (int kt = 0; kt < 4; kt++)
            bF[nt][kt] = *(const bf16x8*)(Wm2T + (nt * 16 + lm) * 128 + kt * 32 + quad * 8);
    float bv[4], w30[4], w31[4];
#pragma unroll
    for (int nt = 0; nt < 4; nt++) {
        int n = nt * 16 + lm;
        bv[nt] = bm2[n]; w30[nt] = Wm3[2 * n]; w31[nt] = Wm3[2 * n + 1];
    }
    float b30 = bm3[0], b31 = bm3[1];

    for (int tile = gw; tile < E_ / 16; tile += nw) {
        int p0 = tile * 16;
        int s = srcv[p0 + lm];
        int d = (int)dstv[p0 + lm];
        const short* pr = Pb + (size_t)s * 128 + quad * 8;
        const short* qr = Qb + (size_t)d * 128 + quad * 8;
        bf16x8 aF[4];
#pragma unroll
        for (int kt = 0; kt < 4; kt++) {
            bf16x8 pv = *(const bf16x8*)(pr + kt * 32);
            bf16x8 qv = *(const bf16x8*)(qr + kt * 32);
            bf16x8 o;
#pragma unroll
            for (int j = 0; j < 8; j++) {
                float x = bf2f(pv[j]) + bf2f(qv[j]);
                o[j] = f2bf(fmaxf(x, 0.f));
            }
            aF[kt] = o;
        }
        floatx4 acc[4];
#pragma unroll
        for (int nt = 0; nt < 4; nt++) {
            acc[nt] = (floatx4){0.f, 0.f, 0.f, 0.f};
#pragma unroll
            for (int kt = 0; kt < 4; kt++)
                acc[nt] = __builtin_amdgcn_mfma_f32_16x16x32_bf16(aF[kt], bF[nt][kt], acc[nt], 0, 0, 0);
        }
        float pz0[4] = {0.f, 0.f, 0.f, 0.f};
        float pz1[4] = {0.f, 0.f, 0.f, 0.f};
#pragma unroll
        for (int nt = 0; nt < 4; nt++) {
#pragma unroll
            for (int r = 0; r < 4; r++) {
                float u = fmaxf(acc[nt][r] + bv[nt], 0.f);
                pz0[r] += u * w30[nt];
                pz1[r] += u * w31[nt];
            }
        }
#pragma unroll
        for (int off = 1; off < 16; off <<= 1) {
#pragma unroll
            for (int r = 0; r < 4; r++) {
                pz0[r] += __shfl_xor(pz0[r], off);
                pz1[r] += __shfl_xor(pz1[r], off);
            }
        }
        if (lm < 4) {
            int eid = eidv[p0 + quad * 4 + lm];
            float z0 = pz0[lm] + b30;
            float z1 = pz1[lm] + b31;
            if (isinf(z0)) z0 = 1e9f;
            if (isinf(z1)) z1 = 1e9f;
            *(float2*)(zout + (size_t)eid * 2) = make_float2(z0, z1);
        }
    }
}

extern "C" void kernel_launch(void* const* d_in, const int* in_sizes, int n_in,
                              void* d_out, int out_size, void* d_ws, size_t ws_size,
                              hipStream_t stream) {
    const float* h_in  = (const float*)d_in[0];
    const int*   src   = (const int*)d_in[2];
    const int*   dst   = (const int*)d_in[3];
    const float* W_emb = (const float*)d_in[4];
    const float* b_emb = (const float*)d_in[5];
    const float* Wg    = (const float*)d_in[6];
    const float* alg   = (const float*)d_in[7];
    const float* arg_  = (const float*)d_in[8];
    const float* bg    = (const float*)d_in[9];
    const float* gam   = (const float*)d_in[10];
    const float* bet   = (const float*)d_in[11];
    const float* W3    = (const float*)d_in[12];
    const float* al3   = (const float*)d_in[13];
    const float* ar3   = (const float*)d_in[14];
    const float* b3    = (const float*)d_in[15];
    const float* gam3  = (const float*)d_in[16];
    const float* bet3  = (const float*)d_in[17];
    const float* Wa    = (const float*)d_in[18];
    const float* ba    = (const float*)d_in[19];
    const float* Wm1   = (const float*)d_in[20];
    const float* bm1   = (const float*)d_in[21];
    const float* Wm2   = (const float*)d_in[22];
    const float* bm2   = (const float*)d_in[23];
    const float* Wm3   = (const float*)d_in[24];
    const float* bm3   = (const float*)d_in[25];

    float* zout = (float*)d_out;
    float* sout = zout + (size_t)E_ * 2;

    float* ws = (float*)d_ws;
    size_t o = 0;
    float* h_cur = ws + o; o += (size_t)N_ * 128;
    float* xbuf  = ws + o; o += (size_t)N_ * 128;
    float* featb = ws + o; o += (size_t)N_ * 128;   // reused: bf16 feat, coarse partials, bf16 P/Q
    float* el    = ws + o; o += (size_t)N_ * 8;
    float* er    = ws + o; o += (size_t)N_ * 8;
    float* colsum = ws + o; o += 128;
    float* colsq  = ws + o; o += 128;
    float* hc     = ws + o; o += 100 * 128;
    short* Wm2T = (short*)(ws + o); o += (64 * 128) / 2;
    int* counts = (int*)(ws + o); o += N_;
    int* rowptr = (int*)(ws + o); o += N_ + 4;
    int* cursor = (int*)(ws + o); o += N_;
    int* srcv   = (int*)(ws + o); o += E_;
    unsigned short* dstv = (unsigned short*)(ws + o); o += E_ / 2;
    int* eidv   = (int*)(ws + o); o += E_;
    int* bsum   = (int*)(ws + o); o += SNB_ + 4;

    short* featw = (short*)featb;  // bf16 per-layer projection

    // ---- CSR build (parallel 3-phase scan; excl scratch reuses eidv pre-fill) ----
    hipMemsetAsync(counts, 0, N_ * sizeof(int), stream);
    k_count<<<1024, 256, 0, stream>>>(dst, counts);
    k_scanA<<<SNB_, 256, 0, stream>>>(counts, eidv, bsum);
    k_scanB<<<1, 256, 0, stream>>>(bsum);
    k_scanC<<<SNB_ + 1, 256, 0, stream>>>(eidv, bsum, rowptr, cursor);
    k_fill<<<1024, 256, 0, stream>>>(src, dst, cursor, srcv, dstv, eidv);
    k_prep_w<<<32, 256, 0, stream>>>(Wm2, Wm2T);

    // ---- embedding ----
    k_gemm128<<<N_ / 8, 256, 0, stream>>>(h_in, W_emb, b_emb, h_cur);

    // ---- layer 0 (H=8) ----
    k_gemm128b<<<N_ / 8, 256, 0, stream>>>(h_cur, Wg + 0 * 16384, nullptr, featw);
    k_elr<8><<<N_ / 4, 256, 0, stream>>>(featw, alg + 0 * 128, arg_ + 0 * 128, el, er);
    k_gat_agg<8><<<N_ / 4, 256, 0, stream>>>(featw, el, er, rowptr, srcv, bg + 0 * 128, xbuf);
    hipMemsetAsync(colsum, 0, 256 * sizeof(float), stream);
    k_bn_stats<<<512, 256, 0, stream>>>(xbuf, colsum, colsq);
    k_bn_apply<<<(N_ * 128) / 256, 256, 0, stream>>>(xbuf, h_cur, colsum, colsq,
                                                     gam + 0 * 128, bet + 0 * 128, h_cur, 1);

    // ---- layer 1 (biGAT, H=8) ----
    k_gemm100<<<N_ / 8, 256, 0, stream>>>(h_cur, Wa, ba, xbuf);
    k_smax100<<<N_ / 4, 256, 0, stream>>>(xbuf, sout);
    k_gemm128b<<<N_ / 8, 256, 0, stream>>>(h_cur, Wg + 1 * 16384, nullptr, featw);
    k_elr<8><<<N_ / 4, 256, 0, stream>>>(featw, alg + 1 * 128, arg_ + 1 * 128, el, er);
    k_gat_agg<8><<<N_ / 4, 256, 0, stream>>>(featw, el, er, rowptr, srcv, bg + 1 * 128, xbuf);
    hipMemsetAsync(colsum, 0, 256 * sizeof(float), stream);
    k_bn_stats<<<512, 256, 0, stream>>>(xbuf, colsum, colsq);
    k_bn_apply<<<(N_ * 128) / 256, 256, 0, stream>>>(xbuf, h_cur, colsum, colsq,
                                                     gam + 1 * 128, bet + 1 * 128, xbuf, 0);
    k_coarse_part<<<CB_, 512, 0, stream>>>(sout, xbuf, featb);
    k_coarse_reduce<<<50, 256, 0, stream>>>(featb, hc);
    k_combine<<<N_, 128, 0, stream>>>(sout, hc, xbuf, h_cur);

    // ---- layer 2 (H=8) ----
    k_gemm128b<<<N_ / 8, 256, 0, stream>>>(h_cur, Wg + 2 * 16384, nullptr, featw);
    k_elr<8><<<N_ / 4, 256, 0, stream>>>(featw, alg + 2 * 128, arg_ + 2 * 128, el, er);
    k_gat_agg<8><<<N_ / 4, 256, 0, stream>>>(featw, el, er, rowptr, srcv, bg + 2 * 128, xbuf);
    hipMemsetAsync(colsum, 0, 256 * sizeof(float), stream);
    k_bn_stats<<<512, 256, 0, stream>>>(xbuf, colsum, colsq);
    k_bn_apply<<<(N_ * 128) / 256, 256, 0, stream>>>(xbuf, h_cur, colsum, colsq,
                                                     gam + 2 * 128, bet + 2 * 128, h_cur, 1);

    // ---- layer 3 (H=1) ----
    k_gemm128b<<<N_ / 8, 256, 0, stream>>>(h_cur, W3, nullptr, featw);
    k_elr<1><<<N_ / 4, 256, 0, stream>>>(featw, al3, ar3, el, er);
    k_gat_agg<1><<<N_ / 4, 256, 0, stream>>>(featw, el, er, rowptr, srcv, b3, xbuf);
    hipMemsetAsync(colsum, 0, 256 * sizeof(float), stream);
    k_bn_stats<<<512, 256, 0, stream>>>(xbuf, colsum, colsq);
    k_bn_apply<<<(N_ * 128) / 256, 256, 0, stream>>>(xbuf, h_cur, colsum, colsq,
                                                     gam3, bet3, h_cur, 1);

    // ---- edge MLP readout: Pb = bf16(h@Wm1[:128]+bm1), Qb = bf16(h@Wm1[128:]) ----
    short* Pb = (short*)featb;
    short* Qb = Pb + (size_t)N_ * 128;
    k_gemm128b<<<N_ / 8, 256, 0, stream>>>(h_cur, Wm1, bm1, Pb);
    k_gemm128b<<<N_ / 8, 256, 0, stream>>>(h_cur, Wm1 + 128 * 128, nullptr, Qb);
    k_edge_mlp3<<<2048, 256, 0, stream>>>(Pb, Qb, srcv, dstv, eidv, Wm2T, bm2, Wm3, bm3, zout);
}

// Round 13
// 942.938 us; speedup vs baseline: 1.2426x; 1.1405x over previous
//
#include <hip/hip_runtime.h>
#include <hip/hip_bf16.h>
#include <math.h>

#define N_ 40000
#define E_ 640000
#define CB_ 400   // k_coarse partial blocks
#define CR_ 100   // rows per block (CB_*CR_ == N_)
#define SB_ 256
#define SNB_ 157  // ceil(N_/SB_)

typedef short bf16x8 __attribute__((ext_vector_type(8)));
typedef float floatx4 __attribute__((ext_vector_type(4)));

__device__ __forceinline__ short f2bf(float f) {
    __hip_bfloat16 h = __float2bfloat16(f);
    return *reinterpret_cast<short*>(&h);
}
__device__ __forceinline__ float bf2f(short u) {
    unsigned int x = ((unsigned int)(unsigned short)u) << 16;
    return __int_as_float(x);
}
__device__ __forceinline__ float rdlane(float v, int l) {
    return __int_as_float(__builtin_amdgcn_readlane(__float_as_int(v), l));
}
// unpack 2 bf16 packed in a uint
__device__ __forceinline__ float bflo(unsigned int u) { return __int_as_float(u << 16); }
__device__ __forceinline__ float bfhi(unsigned int u) { return __int_as_float(u & 0xffff0000u); }

// ---------------- CSR build ----------------
__global__ void k_count(const int* __restrict__ dst, int* __restrict__ counts) {
    for (int e = blockIdx.x * blockDim.x + threadIdx.x; e < E_; e += gridDim.x * blockDim.x)
        atomicAdd(&counts[dst[e]], 1);
}

// ---- 3-phase parallel scan ----
__global__ __launch_bounds__(256) void k_scanA(const int* __restrict__ counts,
                                               int* __restrict__ excl,
                                               int* __restrict__ bsum) {
    int t = threadIdx.x;
    int i = blockIdx.x * SB_ + t;
    int v = (i < N_) ? counts[i] : 0;
    int lane = t & 63, wv = t >> 6;
    int x = v;
#pragma unroll
    for (int off = 1; off < 64; off <<= 1) {
        int y = __shfl_up(x, off);
        if (lane >= off) x += y;
    }
    __shared__ int wsum[4];
    __shared__ int woff[4];
    if (lane == 63) wsum[wv] = x;
    __syncthreads();
    if (t == 0) {
        int a = 0;
#pragma unroll
        for (int j = 0; j < 4; j++) { int tv = wsum[j]; woff[j] = a; a += tv; }
        bsum[blockIdx.x] = a;
    }
    __syncthreads();
    if (i < N_) excl[i] = x - v + woff[wv];
}

__global__ __launch_bounds__(256) void k_scanB(int* __restrict__ bsum) {
    int t = threadIdx.x;
    int v = (t < SNB_) ? bsum[t] : 0;
    int lane = t & 63, wv = t >> 6;
    int x = v;
#pragma unroll
    for (int off = 1; off < 64; off <<= 1) {
        int y = __shfl_up(x, off);
        if (lane >= off) x += y;
    }
    __shared__ int wsum[4];
    __shared__ int woff[4];
    if (lane == 63) wsum[wv] = x;
    __syncthreads();
    if (t == 0) {
        int a = 0;
#pragma unroll
        for (int j = 0; j < 4; j++) { int tv = wsum[j]; woff[j] = a; a += tv; }
    }
    __syncthreads();
    if (t < SNB_) bsum[t] = x - v + woff[wv];
}

__global__ __launch_bounds__(256) void k_scanC(const int* __restrict__ excl,
                                               const int* __restrict__ bsum,
                                               int* __restrict__ rowptr,
                                               int* __restrict__ cursor) {
    int i = blockIdx.x * 256 + threadIdx.x;
    if (i < N_) {
        int r = excl[i] + bsum[i / SB_];
        rowptr[i] = r;
        cursor[i] = r;
    }
    if (i == N_) rowptr[N_] = E_;
}

__global__ void k_fill(const int* __restrict__ src, const int* __restrict__ dst,
                       int* __restrict__ cursor, int* __restrict__ srcv,
                       unsigned short* __restrict__ dstv, int* __restrict__ eidv) {
    for (int e = blockIdx.x * blockDim.x + threadIdx.x; e < E_; e += gridDim.x * blockDim.x) {
        int d = dst[e];
        int pos = atomicAdd(&cursor[d], 1);
        srcv[pos] = src[e];
        dstv[pos] = (unsigned short)d;
        eidv[pos] = e;
    }
}

// ---------------- GEMM [N,128] x [128,128] (+bias), fp32 out (embedding) ----------------
__global__ __launch_bounds__(256) void k_gemm128(const float* __restrict__ A,
                                                 const float* __restrict__ W,
                                                 const float* __restrict__ bias,
                                                 float* __restrict__ C) {
    __shared__ float As[8 * 128];
    int t = threadIdx.x;
    int r0 = blockIdx.x * 8;
    *(float4*)(As + t * 4) = *(const float4*)(A + (size_t)r0 * 128 + t * 4);
    __syncthreads();
    int c = t & 127, g = t >> 7;
    float a0 = 0.f, a1 = 0.f, a2 = 0.f, a3 = 0.f;
#pragma unroll 4
    for (int k = 0; k < 128; k++) {
        float wv = W[k * 128 + c];
        a0 += As[(g * 4 + 0) * 128 + k] * wv;
        a1 += As[(g * 4 + 1) * 128 + k] * wv;
        a2 += As[(g * 4 + 2) * 128 + k] * wv;
        a3 += As[(g * 4 + 3) * 128 + k] * wv;
    }
    float bv = bias ? bias[c] : 0.f;
    C[(size_t)(r0 + g * 4 + 0) * 128 + c] = a0 + bv;
    C[(size_t)(r0 + g * 4 + 1) * 128 + c] = a1 + bv;
    C[(size_t)(r0 + g * 4 + 2) * 128 + c] = a2 + bv;
    C[(size_t)(r0 + g * 4 + 3) * 128 + c] = a3 + bv;
}

// ---------------- prep: 6x fp32 [k=128][n=128] -> bf16 [n][k] ----------------
__global__ __launch_bounds__(256) void k_prep_all(const float* __restrict__ Wg,
                                                  const float* __restrict__ W3,
                                                  const float* __restrict__ Wm1,
                                                  short* __restrict__ WbT6) {
    int i = blockIdx.x * 256 + threadIdx.x;   // 6*16384 total
    if (i >= 6 * 16384) return;
    int m = i >> 14;
    int r = i & 16383;
    int n = r >> 7, k = r & 127;
    const float* srcp;
    switch (m) {
        case 0: srcp = Wg; break;
        case 1: srcp = Wg + 16384; break;
        case 2: srcp = Wg + 32768; break;
        case 3: srcp = W3; break;
        case 4: srcp = Wm1; break;
        default: srcp = Wm1 + 16384; break;
    }
    WbT6[m * 16384 + n * 128 + k] = f2bf(srcp[k * 128 + n]);
}

// ---------------- MFMA GEMM: [N,128](fp32) @ WbT(bf16 [n][k]) -> bf16 out ----------------
// 64 rows/block, full N=128. A converted fp32->bf16 into LDS (+8 pad = 2-way bank, free).
// Fragment & C mapping identical to validated k_edge_mlp3 pattern.
__global__ __launch_bounds__(256) void k_gemm_mfma(const float* __restrict__ A,
                                                   const short* __restrict__ WbT,
                                                   const float* __restrict__ bias,
                                                   short* __restrict__ C) {
    __shared__ short sA[64 * 136];
    __shared__ short sB[128 * 136];
    int t = threadIdx.x;
    int r0 = blockIdx.x * 64;
    // stage B: each thread copies 64 bf16
    {
        int n = t >> 1;
        int k0 = (t & 1) * 64;
#pragma unroll
        for (int j = 0; j < 8; j++) {
            bf16x8 v = *(const bf16x8*)(WbT + n * 128 + k0 + 8 * j);
            *(bf16x8*)(sB + n * 136 + k0 + 8 * j) = v;
        }
    }
    // stage A: each thread converts 32 floats
    {
        int r = t >> 2;
        int k0 = (t & 3) * 32;
        const float* ar = A + (size_t)(r0 + r) * 128 + k0;
#pragma unroll
        for (int j = 0; j < 4; j++) {
            float4 f0 = *(const float4*)(ar + 8 * j);
            float4 f1 = *(const float4*)(ar + 8 * j + 4);
            bf16x8 v;
            v[0] = f2bf(f0.x); v[1] = f2bf(f0.y); v[2] = f2bf(f0.z); v[3] = f2bf(f0.w);
            v[4] = f2bf(f1.x); v[5] = f2bf(f1.y); v[6] = f2bf(f1.z); v[7] = f2bf(f1.w);
            *(bf16x8*)(sA + r * 136 + k0 + 8 * j) = v;
        }
    }
    __syncthreads();
    int lane = t & 63, wv = t >> 6;
    int lm = lane & 15, quad = lane >> 4;
    int m0 = wv * 16;
    bf16x8 aF[4];
#pragma unroll
    for (int kt = 0; kt < 4; kt++)
        aF[kt] = *(const bf16x8*)(sA + (m0 + lm) * 136 + kt * 32 + quad * 8);
#pragma unroll
    for (int nt = 0; nt < 8; nt++) {
        floatx4 acc = (floatx4){0.f, 0.f, 0.f, 0.f};
#pragma unroll
        for (int kt = 0; kt < 4; kt++) {
            bf16x8 bF = *(const bf16x8*)(sB + (nt * 16 + lm) * 136 + kt * 32 + quad * 8);
            acc = __builtin_amdgcn_mfma_f32_16x16x32_bf16(aF[kt], bF, acc, 0, 0, 0);
        }
        int col = nt * 16 + lm;
        float bv = bias ? bias[col] : 0.f;
#pragma unroll
        for (int r = 0; r < 4; r++) {
            int row = r0 + m0 + quad * 4 + r;
            C[(size_t)row * 128 + col] = f2bf(acc[r] + bv);
        }
    }
}

// ---------------- logits GEMM [N,128] x [128,100] (+bias) ----------------
__global__ __launch_bounds__(256) void k_gemm100(const float* __restrict__ A,
                                                 const float* __restrict__ W,
                                                 const float* __restrict__ bias,
                                                 float* __restrict__ C) {
    __shared__ float As[8 * 128];
    int t = threadIdx.x;
    int r0 = blockIdx.x * 8;
    *(float4*)(As + t * 4) = *(const float4*)(A + (size_t)r0 * 128 + t * 4);
    __syncthreads();
    int c = t & 127, g = t >> 7;
    if (c >= 100) return;
    float a0 = 0.f, a1 = 0.f, a2 = 0.f, a3 = 0.f;
#pragma unroll 4
    for (int k = 0; k < 128; k++) {
        float wv = W[k * 100 + c];
        a0 += As[(g * 4 + 0) * 128 + k] * wv;
        a1 += As[(g * 4 + 1) * 128 + k] * wv;
        a2 += As[(g * 4 + 2) * 128 + k] * wv;
        a3 += As[(g * 4 + 3) * 128 + k] * wv;
    }
    float bv = bias[c];
    C[(size_t)(r0 + g * 4 + 0) * 100 + c] = a0 + bv;
    C[(size_t)(r0 + g * 4 + 1) * 100 + c] = a1 + bv;
    C[(size_t)(r0 + g * 4 + 2) * 100 + c] = a2 + bv;
    C[(size_t)(r0 + g * 4 + 3) * 100 + c] = a3 + bv;
}

// ---------------- softmax over 100 logits, wave per node, barrier-free ----------------
__global__ __launch_bounds__(256) void k_smax100(const float* __restrict__ logits,
                                                 float* __restrict__ s) {
    int lane = threadIdx.x & 63;
    int n = blockIdx.x * 4 + (threadIdx.x >> 6);
    if (n >= N_) return;
    bool act = lane < 50;
    float2 v = make_float2(-INFINITY, -INFINITY);
    if (act) v = *(const float2*)(logits + (size_t)n * 100 + 2 * lane);
    float mx = fmaxf(v.x, v.y);
#pragma unroll
    for (int off = 1; off < 64; off <<= 1) mx = fmaxf(mx, __shfl_xor(mx, off));
    float e0 = act ? __expf(v.x - mx) : 0.f;
    float e1 = act ? __expf(v.y - mx) : 0.f;
    float sm = e0 + e1;
#pragma unroll
    for (int off = 1; off < 64; off <<= 1) sm += __shfl_xor(sm, off);
    float inv = 1.f / sm;
    if (act) *(float2*)(s + (size_t)n * 100 + 2 * lane) = make_float2(e0 * inv, e1 * inv);
}

// ---------------- per-node attention logits el/er (bf16 feat) ----------------
template <int H>
__global__ __launch_bounds__(256) void k_elr(const short* __restrict__ feat,
                                             const float* __restrict__ al,
                                             const float* __restrict__ ar,
                                             float* __restrict__ el, float* __restrict__ er) {
    int lane = threadIdx.x & 63;
    int n = blockIdx.x * 4 + (threadIdx.x >> 6);
    if (n >= N_) return;
    unsigned int u = *(const unsigned int*)(feat + (size_t)n * 128 + 2 * lane);
    float fx = bflo(u), fy = bfhi(u);
    float2 a = *(const float2*)(al + 2 * lane);
    float2 b = *(const float2*)(ar + 2 * lane);
    float pl = fx * a.x + fy * a.y;
    float pr = fx * b.x + fy * b.y;
    constexpr int G = 64 / H;
#pragma unroll
    for (int off = 1; off < G; off <<= 1) {
        pl += __shfl_xor(pl, off);
        pr += __shfl_xor(pr, off);
    }
    if ((lane & (G - 1)) == 0) {
        int hh = lane / G;
        el[(size_t)n * H + hh] = pl;
        er[(size_t)n * H + hh] = pr;
    }
}

// ---------------- GAT edge-softmax + aggregate (wave per dst node, bf16 feat) ----------------
template <int H>
__global__ __launch_bounds__(256) void k_gat_agg(const short* __restrict__ feat,
                                                 const float* __restrict__ el,
                                                 const float* __restrict__ er,
                                                 const int* __restrict__ rowptr,
                                                 const int* __restrict__ srcv,
                                                 const float* __restrict__ bias,
                                                 float* __restrict__ xout) {
    int lane = threadIdx.x & 63;
    int n = blockIdx.x * 4 + (threadIdx.x >> 6);
    if (n >= N_) return;
    int beg = rowptr[n], end = rowptr[n + 1];
    int f0 = 2 * lane;
    if (beg == end) {
        *(float2*)(xout + (size_t)n * 128 + f0) = *(const float2*)(bias + f0);
        return;
    }
    constexpr int LH = (H == 8) ? 3 : 0;
    int h = lane & (H - 1);
    float ern = er[(size_t)n * H + h];
    float m = -INFINITY, ss = 0.f;
    for (int e = beg + (lane >> LH); e < end; e += (64 >> LH)) {
        int sI = srcv[e];
        float x = el[(size_t)sI * H + h] + ern;
        float lr = x > 0.f ? x : 0.2f * x;
        if (lr > m) { ss = ss * __expf(m - lr) + 1.f; m = lr; }
        else ss += __expf(lr - m);
    }
#pragma unroll
    for (int off = H; off < 64; off <<= 1) {
        float om = __shfl_xor(m, off);
        float os = __shfl_xor(ss, off);
        float nm = fmaxf(m, om);
        float p1 = (m == -INFINITY) ? 0.f : ss * __expf(m - nm);
        float p2 = (om == -INFINITY) ? 0.f : os * __expf(om - nm);
        m = nm; ss = p1 + p2;
    }
    int hf = (lane * H) >> 6;
    float mh = __shfl(m, hf);
    float dh = __shfl(ss, hf);
    float inv_d = 1.f / dh;
    float ernf = er[(size_t)n * H + hf];
    float accx = 0.f, accy = 0.f;
    int e = beg;
    for (; e + 2 <= end; e += 2) {
        int s0 = srcv[e], s1 = srcv[e + 1];
        float x0 = el[(size_t)s0 * H + hf] + ernf;
        float x1 = el[(size_t)s1 * H + hf] + ernf;
        unsigned int u0 = *(const unsigned int*)(feat + (size_t)s0 * 128 + f0);
        unsigned int u1 = *(const unsigned int*)(feat + (size_t)s1 * 128 + f0);
        float lr0 = x0 > 0.f ? x0 : 0.2f * x0;
        float lr1 = x1 > 0.f ? x1 : 0.2f * x1;
        float a0 = __expf(lr0 - mh) * inv_d;
        float a1 = __expf(lr1 - mh) * inv_d;
        accx += a0 * bflo(u0) + a1 * bflo(u1);
        accy += a0 * bfhi(u0) + a1 * bfhi(u1);
    }
    if (e < end) {
        int s0 = srcv[e];
        float x0 = el[(size_t)s0 * H + hf] + ernf;
        unsigned int u0 = *(const unsigned int*)(feat + (size_t)s0 * 128 + f0);
        float lr0 = x0 > 0.f ? x0 : 0.2f * x0;
        float a0 = __expf(lr0 - mh) * inv_d;
        accx += a0 * bflo(u0);
        accy += a0 * bfhi(u0);
    }
    float2 b2 = *(const float2*)(bias + f0);
    *(float2*)(xout + (size_t)n * 128 + f0) = make_float2(accx + b2.x, accy + b2.y);
}

// ---------------- BN stats ----------------
__global__ __launch_bounds__(256) void k_bn_stats(const float* __restrict__ x,
                                                  float* __restrict__ sum,
                                                  float* __restrict__ sumsq) {
    __shared__ float ls[256], lq[256];
    int t = threadIdx.x;
    int col = t & 127, half = t >> 7;
    float s = 0.f, q = 0.f;
    for (int r = blockIdx.x * 2 + half; r < N_; r += gridDim.x * 2) {
        float v = x[(size_t)r * 128 + col];
        s += v; q += v * v;
    }
    ls[t] = s; lq[t] = q;
    __syncthreads();
    if (t < 128) {
        atomicAdd(&sum[col], ls[t] + ls[t + 128]);
        atomicAdd(&sumsq[col], lq[t] + lq[t + 128]);
    }
}

// ---------------- BN apply + ELU + residual (+mask) ----------------
__global__ __launch_bounds__(256) void k_bn_apply(const float* __restrict__ x,
                                                  const float* __restrict__ hprev,
                                                  const float* __restrict__ sum,
                                                  const float* __restrict__ sumsq,
                                                  const float* __restrict__ g,
                                                  const float* __restrict__ b,
                                                  float* __restrict__ out, int do_mask) {
    int i = blockIdx.x * blockDim.x + threadIdx.x;
    if (i >= N_ * 128) return;
    int c = i & 127;
    const float invN = 1.f / (float)N_;
    float mu = sum[c] * invN;
    float var = sumsq[c] * invN - mu * mu;
    float inv = rsqrtf(var + 1e-5f);
    float y = g[c] * (x[i] - mu) * inv + b[c];
    y = y > 0.f ? y : (__expf(y) - 1.f);
    float hv = hprev[i] + y;
    if (do_mask && isinf(hv)) hv = 1e9f;
    out[i] = hv;
}

// ---------------- h_coarse partials ----------------
__global__ __launch_bounds__(512) void k_coarse_part(const float* __restrict__ s,
                                                     const float* __restrict__ hf,
                                                     float* __restrict__ part) {
    int t = threadIdx.x;
    int c = t & 127;
    int g = t >> 7;        // 0..3
    int lane = t & 63;
    float acc[25];
#pragma unroll
    for (int a = 0; a < 25; a++) acc[a] = 0.f;
    int n0 = blockIdx.x * CR_;
    for (int n = n0; n < n0 + CR_; n += 2) {
        float hv0 = hf[(size_t)n * 128 + c];
        float hv1 = hf[(size_t)(n + 1) * 128 + c];
        float sv0 = 0.f, sv1 = 0.f;
        if (lane < 25) {
            sv0 = s[(size_t)n * 100 + 25 * g + lane];
            sv1 = s[(size_t)(n + 1) * 100 + 25 * g + lane];
        }
#pragma unroll
        for (int a = 0; a < 25; ++a) {
            float a0 = rdlane(sv0, a);
            float a1 = rdlane(sv1, a);
            acc[a] += a0 * hv0 + a1 * hv1;
        }
    }
    float* dstp = part + (size_t)blockIdx.x * 12800 + (size_t)(25 * g) * 128 + c;
#pragma unroll
    for (int a = 0; a < 25; a++) dstp[a * 128] = acc[a];
}

// ---------------- reduce partials -> hc[100][128] ----------------
__global__ __launch_bounds__(256) void k_coarse_reduce(const float* __restrict__ part,
                                                       float* __restrict__ hc) {
    int i = blockIdx.x * blockDim.x + threadIdx.x;  // 12800 total
    if (i >= 12800) return;
    float s0 = 0.f, s1 = 0.f, s2 = 0.f, s3 = 0.f;
    for (int b = 0; b < CB_; b += 4) {
        s0 += part[(size_t)(b + 0) * 12800 + i];
        s1 += part[(size_t)(b + 1) * 12800 + i];
        s2 += part[(size_t)(b + 2) * 12800 + i];
        s3 += part[(size_t)(b + 3) * 12800 + i];
    }
    hc[i] = (s0 + s1) + (s2 + s3);
}

// ---------------- h = mask(0.5*h_fine + 0.5*(s@h_coarse)) ----------------
__global__ __launch_bounds__(128) void k_combine(const float* __restrict__ s,
                                                 const float* __restrict__ hc,
                                                 const float* __restrict__ hfine,
                                                 float* __restrict__ hout) {
    __shared__ float ssh[100];
    int n = blockIdx.x, t = threadIdx.x;
    if (t < 100) ssh[t] = s[(size_t)n * 100 + t];
    __syncthreads();
    float acc = 0.f;
    for (int a = 0; a < 100; a++) acc += ssh[a] * hc[a * 128 + t];
    float v = 0.5f * hfine[(size_t)n * 128 + t] + 0.5f * acc;
    if (isinf(v)) v = 1e9f;
    hout[(size_t)n * 128 + t] = v;
}

// ---------------- prep: Wm2 [128][64] fp32 -> Wm2T bf16 [64][128] ----------------
__global__ __launch_bounds__(256) void k_prep_w(const float* __restrict__ Wm2,
                                                short* __restrict__ Wm2T) {
    int i = blockIdx.x * blockDim.x + threadIdx.x;  // 8192 total
    if (i >= 64 * 128) return;
    int n = i & 63, k = i >> 6;
    Wm2T[n * 128 + k] = f2bf(Wm2[k * 64 + n]);
}

// ---------------- edge MLP readout: dst-sorted order, barrier-free persistent MFMA ----------------
__global__ __launch_bounds__(256) void k_edge_mlp3(const short* __restrict__ Pb,
                                                   const short* __restrict__ Qb,
                                                   const int* __restrict__ srcv,
                                                   const unsigned short* __restrict__ dstv,
                                                   const int* __restrict__ eidv,
                                                   const short* __restrict__ Wm2T,
                                                   const float* __restrict__ bm2,
                                                   const float* __restrict__ Wm3,
                                                   const float* __restrict__ bm3,
                                                   float* __restrict__ zout) {
    int lane = threadIdx.x & 63;
    int lm = lane & 15, quad = lane >> 4;
    int gw = (blockIdx.x * blockDim.x + threadIdx.x) >> 6;
    int nw = (gridDim.x * blockDim.x) >> 6;

    bf16x8 bF[4][4];
#pragma unroll
    for (int nt = 0; nt < 4; nt++)
#pragma unroll
        for (int kt = 0; kt < 4; kt++)
            bF[nt][kt] = *(const bf16x8*)(Wm2T + (nt * 16 + lm) * 128 + kt * 32 + quad * 8);
    float bv[4], w30[4], w31[4];
#pragma unroll
    for (int nt = 0; nt < 4; nt++) {
        int n = nt * 16 + lm;
        bv[nt] = bm2[n]; w30[nt] = Wm3[2 * n]; w31[nt] = Wm3[2 * n + 1];
    }
    float b30 = bm3[0], b31 = bm3[1];

    for (int tile = gw; tile < E_ / 16; tile += nw) {
        int p0 = tile * 16;
        int s = srcv[p0 + lm];
        int d = (int)dstv[p0 + lm];
        const short* pr = Pb + (size_t)s * 128 + quad * 8;
        const short* qr = Qb + (size_t)d * 128 + quad * 8;
        bf16x8 aF[4];
#pragma unroll
        for (int kt = 0; kt < 4; kt++) {
            bf16x8 pv = *(const bf16x8*)(pr + kt * 32);
            bf16x8 qv = *(const bf16x8*)(qr + kt * 32);
            bf16x8 o;
#pragma unroll
            for (int j = 0; j < 8; j++) {
                float x = bf2f(pv[j]) + bf2f(qv[j]);
                o[j] = f2bf(fmaxf(x, 0.f));
            }
            aF[kt] = o;
        }
        floatx4 acc[4];
#pragma unroll
        for (int nt = 0; nt < 4; nt++) {
            acc[nt] = (floatx4){0.f, 0.f, 0.f, 0.f};
#pragma unroll
            for (int kt = 0; kt < 4; kt++)
                acc[nt] = __builtin_amdgcn_mfma_f32_16x16x32_bf16(aF[kt], bF[nt][kt], acc[nt], 0, 0, 0);
        }
        float pz0[4] = {0.f, 0.f, 0.f, 0.f};
        float pz1[4] = {0.f, 0.f, 0.f, 0.f};
#pragma unroll
        for (int nt = 0; nt < 4; nt++) {
#pragma unroll
            for (int r = 0; r < 4; r++) {
                float u = fmaxf(acc[nt][r] + bv[nt], 0.f);
                pz0[r] += u * w30[nt];
                pz1[r] += u * w31[nt];
            }
        }
#pragma unroll
        for (int off = 1; off < 16; off <<= 1) {
#pragma unroll
            for (int r = 0; r < 4; r++) {
                pz0[r] += __shfl_xor(pz0[r], off);
                pz1[r] += __shfl_xor(pz1[r], off);
            }
        }
        if (lm < 4) {
            int eid = eidv[p0 + quad * 4 + lm];
            float z0 = pz0[lm] + b30;
            float z1 = pz1[lm] + b31;
            if (isinf(z0)) z0 = 1e9f;
            if (isinf(z1)) z1 = 1e9f;
            *(float2*)(zout + (size_t)eid * 2) = make_float2(z0, z1);
        }
    }
}

extern "C" void kernel_launch(void* const* d_in, const int* in_sizes, int n_in,
                              void* d_out, int out_size, void* d_ws, size_t ws_size,
                              hipStream_t stream) {
    const float* h_in  = (const float*)d_in[0];
    const int*   src   = (const int*)d_in[2];
    const int*   dst   = (const int*)d_in[3];
    const float* W_emb = (const float*)d_in[4];
    const float* b_emb = (const float*)d_in[5];
    const float* Wg    = (const float*)d_in[6];
    const float* alg   = (const float*)d_in[7];
    const float* arg_  = (const float*)d_in[8];
    const float* bg    = (const float*)d_in[9];
    const float* gam   = (const float*)d_in[10];
    const float* bet   = (const float*)d_in[11];
    const float* W3    = (const float*)d_in[12];
    const float* al3   = (const float*)d_in[13];
    const float* ar3   = (const float*)d_in[14];
    const float* b3    = (const float*)d_in[15];
    const float* gam3  = (const float*)d_in[16];
    const float* bet3  = (const float*)d_in[17];
    const float* Wa    = (const float*)d_in[18];
    const float* ba    = (const float*)d_in[19];
    const float* Wm1   = (const float*)d_in[20];
    const float* bm1   = (const float*)d_in[21];
    const float* Wm2   = (const float*)d_in[22];
    const float* bm2   = (const float*)d_in[23];
    const float* Wm3   = (const float*)d_in[24];
    const float* bm3   = (const float*)d_in[25];

    float* zout = (float*)d_out;
    float* sout = zout + (size_t)E_ * 2;

    float* ws = (float*)d_ws;
    size_t o = 0;
    float* h_cur = ws + o; o += (size_t)N_ * 128;
    float* xbuf  = ws + o; o += (size_t)N_ * 128;
    float* featb = ws + o; o += (size_t)N_ * 128;   // reused: bf16 feat, coarse partials, bf16 P/Q
    float* el    = ws + o; o += (size_t)N_ * 8;
    float* er    = ws + o; o += (size_t)N_ * 8;
    float* colsum = ws + o; o += 128;
    float* colsq  = ws + o; o += 128;
    float* hc     = ws + o; o += 100 * 128;
    short* Wm2T = (short*)(ws + o); o += (64 * 128) / 2;
    short* WbT6 = (short*)(ws + o); o += (6 * 16384) / 2;
    int* counts = (int*)(ws + o); o += N_;
    int* rowptr = (int*)(ws + o); o += N_ + 4;
    int* cursor = (int*)(ws + o); o += N_;
    int* srcv   = (int*)(ws + o); o += E_;
    unsigned short* dstv = (unsigned short*)(ws + o); o += E_ / 2;
    int* eidv   = (int*)(ws + o); o += E_;
    int* bsum   = (int*)(ws + o); o += SNB_ + 4;

    short* featw = (short*)featb;  // bf16 per-layer projection

    // ---- CSR build (parallel scan; excl scratch reuses eidv pre-fill) ----
    hipMemsetAsync(counts, 0, N_ * sizeof(int), stream);
    k_count<<<1024, 256, 0, stream>>>(dst, counts);
    k_scanA<<<SNB_, 256, 0, stream>>>(counts, eidv, bsum);
    k_scanB<<<1, 256, 0, stream>>>(bsum);
    k_scanC<<<SNB_ + 1, 256, 0, stream>>>(eidv, bsum, rowptr, cursor);
    k_fill<<<1024, 256, 0, stream>>>(src, dst, cursor, srcv, dstv, eidv);
    k_prep_w<<<32, 256, 0, stream>>>(Wm2, Wm2T);
    k_prep_all<<<384, 256, 0, stream>>>(Wg, W3, Wm1, WbT6);

    // ---- embedding (fp32 for accuracy) ----
    k_gemm128<<<N_ / 8, 256, 0, stream>>>(h_in, W_emb, b_emb, h_cur);

    // ---- layer 0 (H=8) ----
    k_gemm_mfma<<<N_ / 64, 256, 0, stream>>>(h_cur, WbT6 + 0 * 16384, nullptr, featw);
    k_elr<8><<<N_ / 4, 256, 0, stream>>>(featw, alg + 0 * 128, arg_ + 0 * 128, el, er);
    k_gat_agg<8><<<N_ / 4, 256, 0, stream>>>(featw, el, er, rowptr, srcv, bg + 0 * 128, xbuf);
    hipMemsetAsync(colsum, 0, 256 * sizeof(float), stream);
    k_bn_stats<<<512, 256, 0, stream>>>(xbuf, colsum, colsq);
    k_bn_apply<<<(N_ * 128) / 256, 256, 0, stream>>>(xbuf, h_cur, colsum, colsq,
                                                     gam + 0 * 128, bet + 0 * 128, h_cur, 1);

    // ---- layer 1 (biGAT, H=8) ----
    k_gemm100<<<N_ / 8, 256, 0, stream>>>(h_cur, Wa, ba, xbuf);
    k_smax100<<<N_ / 4, 256, 0, stream>>>(xbuf, sout);
    k_gemm_mfma<<<N_ / 64, 256, 0, stream>>>(h_cur, WbT6 + 1 * 16384, nullptr, featw);
    k_elr<8><<<N_ / 4, 256, 0, stream>>>(featw, alg + 1 * 128, arg_ + 1 * 128, el, er);
    k_gat_agg<8><<<N_ / 4, 256, 0, stream>>>(featw, el, er, rowptr, srcv, bg + 1 * 128, xbuf);
    hipMemsetAsync(colsum, 0, 256 * sizeof(float), stream);
    k_bn_stats<<<512, 256, 0, stream>>>(xbuf, colsum, colsq);
    k_bn_apply<<<(N_ * 128) / 256, 256, 0, stream>>>(xbuf, h_cur, colsum, colsq,
                                                     gam + 1 * 128, bet + 1 * 128, xbuf, 0);
    k_coarse_part<<<CB_, 512, 0, stream>>>(sout, xbuf, featb);
    k_coarse_reduce<<<50, 256, 0, stream>>>(featb, hc);
    k_combine<<<N_, 128, 0, stream>>>(sout, hc, xbuf, h_cur);

    // ---- layer 2 (H=8) ----
    k_gemm_mfma<<<N_ / 64, 256, 0, stream>>>(h_cur, WbT6 + 2 * 16384, nullptr, featw);
    k_elr<8><<<N_ / 4, 256, 0, stream>>>(featw, alg + 2 * 128, arg_ + 2 * 128, el, er);
    k_gat_agg<8><<<N_ / 4, 256, 0, stream>>>(featw, el, er, rowptr, srcv, bg + 2 * 128, xbuf);
    hipMemsetAsync(colsum, 0, 256 * sizeof(float), stream);
    k_bn_stats<<<512, 256, 0, stream>>>(xbuf, colsum, colsq);
    k_bn_apply<<<(N_ * 128) / 256, 256, 0, stream>>>(xbuf, h_cur, colsum, colsq,
                                                     gam + 2 * 128, bet + 2 * 128, h_cur, 1);

    // ---- layer 3 (H=1) ----
    k_gemm_mfma<<<N_ / 64, 256, 0, stream>>>(h_cur, WbT6 + 3 * 16384, nullptr, featw);
    k_elr<1><<<N_ / 4, 256, 0, stream>>>(featw, al3, ar3, el, er);
    k_gat_agg<1><<<N_ / 4, 256, 0, stream>>>(featw, el, er, rowptr, srcv, b3, xbuf);
    hipMemsetAsync(colsum, 0, 256 * sizeof(float), stream);
    k_bn_stats<<<512, 256, 0, stream>>>(xbuf, colsum, colsq);
    k_bn_apply<<<(N_ * 128) / 256, 256, 0, stream>>>(xbuf, h_cur, colsum, colsq,
                                                     gam3, bet3, h_cur, 1);

    // ---- edge MLP readout: Pb = bf16(h@Wm1[:128]+bm1), Qb = bf16(h@Wm1[128:]) ----
    short* Pb = (short*)featb;
    short* Qb = Pb + (size_t)N_ * 128;
    k_gemm_mfma<<<N_ / 64, 256, 0, stream>>>(h_cur, WbT6 + 4 * 16384, bm1, Pb);
    k_gemm_mfma<<<N_ / 64, 256, 0, stream>>>(h_cur, WbT6 + 5 * 16384, nullptr, Qb);
    k_edge_mlp3<<<2048, 256, 0, stream>>>(Pb, Qb, srcv, dstv, eidv, Wm2T, bm2, Wm3, bm3, zout);
}